// Round 6
// baseline (629.335 us; speedup 1.0000x reference)
//
#include <hip/hip_runtime.h>

#define NN 100000
#define NE 1600000
#define NE2 1700000
#define OUT_EI 3200000
#define OUT_AL 6600000
#define SLOPE 0.2f
#define NB 391       // ceil(NN/256): dst buckets (256 nodes each)
#define EPB 6400     // edges per block in binning kernel
#define NBB 250      // NE / EPB
#define CAP 5120     // fixed bucket capacity (mean 4096, sigma 64 -> 16 sigma margin)
#define NNP 100096   // NN padded for aliased sub-buffers

typedef unsigned short u16;
typedef unsigned int u32;
typedef __bf16 bf16x8 __attribute__((ext_vector_type(8)));
typedef float f32x4 __attribute__((ext_vector_type(4)));
typedef u32 u32x4 __attribute__((ext_vector_type(4)));

__device__ __forceinline__ float bf2f(u16 u){ return __uint_as_float(((u32)u) << 16); }
__device__ __forceinline__ u16 f2bf(float f){
    u32 x = __float_as_uint(f);
    x += 0x7FFFu + ((x >> 16) & 1u);   // round-to-nearest-even
    return (u16)(x >> 16);
}
__device__ __forceinline__ float eluf(float v){ return v > 0.f ? v : (__expf(v) - 1.f); }
__device__ __forceinline__ float lreluf(float v){ return fmaxf(v, SLOPE * v); }
__device__ __forceinline__ float sel4f(float a, float b, float c, float d, int s){
    float x = (s & 1) ? b : a;
    float y = (s & 1) ? d : c;
    return (s & 2) ? y : x;
}

// ================= edge logits precompute =================
__global__ __launch_bounds__(256) void k_ale(const float* __restrict__ eattr,
                                             const float* __restrict__ W1e, const float* __restrict__ a1e,
                                             const float* __restrict__ W2e, const float* __restrict__ a2e,
                                             u16* __restrict__ ale1, u16* __restrict__ ale2){
    __shared__ float sq1[64], sq2[16];
    int t = threadIdx.x;
    if (t < 64){
        int k = t >> 2, h = t & 3;
        float s = 0.f;
        #pragma unroll 8
        for (int c = 0; c < 32; c++) s += W1e[k * 128 + h * 32 + c] * a1e[h * 32 + c];
        sq1[t] = s;
    }
    if (t < 16){
        float s2 = 0.f;
        #pragma unroll 8
        for (int c = 0; c < 32; c++) s2 += W2e[t * 32 + c] * a2e[c];
        sq2[t] = s2;
    }
    __syncthreads();
    int gt = blockIdx.x * 256 + t;                   // NE*4 exact
    int e = gt >> 2, part = gt & 3;
    f32x4 av = ((const f32x4*)eattr)[(size_t)e * 4 + part];
    int j0 = part * 4;
    float p0 = 0, p1 = 0, p2 = 0, p3 = 0, p4 = 0;
    #pragma unroll
    for (int k = 0; k < 4; k++){
        float a = av[k]; int j = j0 + k;
        p0 += a * sq1[j * 4 + 0]; p1 += a * sq1[j * 4 + 1];
        p2 += a * sq1[j * 4 + 2]; p3 += a * sq1[j * 4 + 3];
        p4 += a * sq2[j];
    }
    #pragma unroll
    for (int m = 1; m < 4; m <<= 1){
        p0 += __shfl_xor(p0, m); p1 += __shfl_xor(p1, m);
        p2 += __shfl_xor(p2, m); p3 += __shfl_xor(p3, m); p4 += __shfl_xor(p4, m);
    }
    if (part == 0){
        ushort4 w; w.x = f2bf(p0); w.y = f2bf(p1); w.z = f2bf(p2); w.w = f2bf(p3);
        ((ushort4*)ale1)[e] = w;
        ale2[e] = f2bf(p4);
    }
}

// ================= bucketed CSR build (fixed-capacity buckets) =================
__global__ __launch_bounds__(256) void k_bscatter(const int* __restrict__ ei, const u16* __restrict__ ale1,
                                                  const u16* __restrict__ ale2,
                                                  int* __restrict__ bcnt, u32* __restrict__ binsP,
                                                  uint2* __restrict__ binsA, u16* __restrict__ binsA2){
    __shared__ int cnt[NB];
    __shared__ int base[NB];
    __shared__ int sdst[EPB];
    int t = threadIdx.x;
    for (int i = t; i < NB; i += 256) cnt[i] = 0;
    __syncthreads();
    int e0 = blockIdx.x * EPB;
    for (int i = t; i < EPB; i += 256){
        int dv = ei[NE + e0 + i];
        sdst[i] = dv;
        atomicAdd(&cnt[dv >> 8], 1);
    }
    __syncthreads();
    for (int i = t; i < NB; i += 256){
        int c = cnt[i];
        base[i] = c ? atomicAdd(&bcnt[i], c) : 0;    // bcnt ends as per-bucket totals
        cnt[i] = 0;
    }
    __syncthreads();
    const uint2* a1 = (const uint2*)ale1;
    for (int i = t; i < EPB; i += 256){
        int e = e0 + i;
        int dst = sdst[i];
        int b = dst >> 8;
        int r = base[b] + atomicAdd(&cnt[b], 1);
        if (r < CAP){                                // 16-sigma guard (never taken for this data)
            size_t pos = (size_t)b * CAP + r;
            binsP[pos] = ((u32)(dst & 255) << 24) | (u32)ei[e];
            binsA[pos] = a1[e];
            binsA2[pos] = ale2[e];
        }
    }
}

// per-bucket: cross-bucket prefix + degree hist + node scan -> offsets + fine scatter
__global__ __launch_bounds__(256) void k_fscatter(const u32* __restrict__ binsP, const uint2* __restrict__ binsA,
                                                  const u16* __restrict__ binsA2, const int* __restrict__ bcnt,
                                                  int* __restrict__ offsets,
                                                  int* __restrict__ src32, uint2* __restrict__ ale1p,
                                                  u16* __restrict__ ale2p){
    __shared__ int sc[512];
    __shared__ int d[256];
    __shared__ int s[256];
    __shared__ int cur[256];
    int t = threadIdx.x, b = blockIdx.x;
    int v0 = (t < NB) ? bcnt[t] : 0;
    int v1 = (t + 256 < NB) ? bcnt[t + 256] : 0;
    sc[t] = v0; sc[t + 256] = v1;
    d[t] = 0;
    __syncthreads();
    #pragma unroll
    for (int dd = 1; dd < 512; dd <<= 1){
        int x0 = (t >= dd) ? sc[t - dd] : 0;
        int x1 = (t + 256 >= dd) ? sc[t + 256 - dd] : 0;
        __syncthreads();
        sc[t] += x0; sc[t + 256] += x1;
        __syncthreads();
    }
    int myCnt = bcnt[b];
    int myBase = sc[b] - myCnt;                      // exclusive prefix of bucket b
    size_t bb = (size_t)b * CAP;
    for (int i = t; i < myCnt; i += 256)
        atomicAdd(&d[binsP[bb + i] >> 24], 1);
    __syncthreads();
    int dv = d[t];
    s[t] = dv; __syncthreads();
    #pragma unroll
    for (int dd = 1; dd < 256; dd <<= 1){
        int x = (t >= dd) ? s[t - dd] : 0;
        __syncthreads();
        s[t] += x;
        __syncthreads();
    }
    int n = b * 256 + t;
    int off = myBase + (s[t] - dv) + n;              // + n: one self-loop slot per preceding node
    if (n < NN) offsets[n] = off;
    cur[t] = off + 1;                                // real edges start after self-loop slot
    if (b == 0 && t == 0) offsets[NN] = NE + NN;
    __syncthreads();
    for (int i = t; i < myCnt; i += 256){
        u32 p = binsP[bb + i];
        int pos = atomicAdd(&cur[p >> 24], 1);
        src32[pos] = (int)(p & 0xFFFFFFu);
        ale1p[pos] = binsA[bb + i];
        ale2p[pos] = binsA2[bb + i];
    }
}

// ================= GEMM 1 (with fused al_s1/al_d1 epilogue) =================
__global__ __launch_bounds__(256) void k_gemm1(const float* __restrict__ x, const float* __restrict__ W,
                                               const float* __restrict__ a1s, const float* __restrict__ a1d,
                                               u16* __restrict__ h1,
                                               float* __restrict__ al_s, float* __restrict__ al_d){
    __shared__ __align__(16) u16 sW[128 * 136];      // transposed: sW[col*136+k]
    int t = threadIdx.x;
    for (int i = t; i < 128 * 128; i += 256){
        int k = i >> 7, c = i & 127;
        sW[c * 136 + k] = f2bf(W[i]);
    }
    __syncthreads();
    int lane = t & 63, wave = t >> 6;
    int quad = lane >> 4, m16 = lane & 15;
    int rowA = blockIdx.x * 64 + wave * 16 + m16;
    bf16x8 afr[4];
    if (rowA < NN){
        const f32x4* xr = (const f32x4*)(x + (size_t)rowA * 128);
        #pragma unroll
        for (int kk = 0; kk < 4; kk++){
            f32x4 va = xr[kk * 8 + quad * 2];
            f32x4 vb = xr[kk * 8 + quad * 2 + 1];
            #pragma unroll
            for (int i2 = 0; i2 < 4; i2++){ afr[kk][i2] = (__bf16)va[i2]; afr[kk][4 + i2] = (__bf16)vb[i2]; }
        }
    } else {
        #pragma unroll
        for (int kk = 0; kk < 4; kk++)
            #pragma unroll
            for (int i2 = 0; i2 < 8; i2++) afr[kk][i2] = (__bf16)0.f;
    }
    int rowbase = blockIdx.x * 64 + wave * 16 + quad * 4;
    float vsA[4][4], vdA[4][4];
    #pragma unroll
    for (int r = 0; r < 4; r++)
        #pragma unroll
        for (int h = 0; h < 4; h++){ vsA[r][h] = 0.f; vdA[r][h] = 0.f; }
    #pragma unroll
    for (int nt = 0; nt < 8; nt++){
        f32x4 acc = (f32x4){0.f, 0.f, 0.f, 0.f};
        const u16* wp = &sW[(nt * 16 + m16) * 136 + quad * 8];
        #pragma unroll
        for (int kk = 0; kk < 4; kk++){
            bf16x8 bfr = *(const bf16x8*)(wp + kk * 32);
            acc = __builtin_amdgcn_mfma_f32_16x16x32_bf16(afr[kk], bfr, acc, 0, 0, 0);
        }
        int col = nt * 16 + m16;
        float cs = a1s[col], cd = a1d[col];
        const int h = nt >> 1;                       // head uniform per nt
        #pragma unroll
        for (int r = 0; r < 4; r++){
            vsA[r][h] += acc[r] * cs;
            vdA[r][h] += acc[r] * cd;
            int row = rowbase + r;
            if (row < NN) h1[(size_t)row * 128 + col] = f2bf(acc[r]);
        }
    }
    #pragma unroll
    for (int r = 0; r < 4; r++)
        #pragma unroll
        for (int h = 0; h < 4; h++)
            #pragma unroll
            for (int m = 1; m < 16; m <<= 1){
                vsA[r][h] += __shfl_xor(vsA[r][h], m);
                vdA[r][h] += __shfl_xor(vdA[r][h], m);
            }
    int rs = m16 >> 2, hs = m16 & 3;                 // lane m16 writes (row rs, head hs)
    float s0 = sel4f(vsA[0][0], vsA[0][1], vsA[0][2], vsA[0][3], hs);
    float s1 = sel4f(vsA[1][0], vsA[1][1], vsA[1][2], vsA[1][3], hs);
    float s2 = sel4f(vsA[2][0], vsA[2][1], vsA[2][2], vsA[2][3], hs);
    float s3 = sel4f(vsA[3][0], vsA[3][1], vsA[3][2], vsA[3][3], hs);
    float d0 = sel4f(vdA[0][0], vdA[0][1], vdA[0][2], vdA[0][3], hs);
    float d1 = sel4f(vdA[1][0], vdA[1][1], vdA[1][2], vdA[1][3], hs);
    float d2 = sel4f(vdA[2][0], vdA[2][1], vdA[2][2], vdA[2][3], hs);
    float d3 = sel4f(vdA[3][0], vdA[3][1], vdA[3][2], vdA[3][3], hs);
    float souts = sel4f(s0, s1, s2, s3, rs);
    float soutd = sel4f(d0, d1, d2, d3, rs);
    int row = rowbase + rs;
    if (row < NN){
        al_s[row * 4 + hs] = souts;
        al_d[row * 4 + hs] = soutd;
    }
}

// ================= layer 1: softmax + aggregate + IN-WAVE gemm2/al2 epilogue =================
// Edge loop identical to r5 (wave-per-node, 16-lane groups, 3-deep pipeline, barrier-free).
// Epilogue: the reduced 128-ch row (duplicated across lane quartets) is staged in a per-wave
// LDS strip (wave-local ordering, NO barrier) and multiplied by the LDS-resident W2 to give
// h2b (bf16) + al_s2/al_d2 directly. h1b and k_gemm2 are eliminated.
__global__ __launch_bounds__(256) void k_node1(const int* __restrict__ src32, const u16* __restrict__ ale1u,
                                               const int* __restrict__ offsets,
                                               const float* __restrict__ al_s, const float* __restrict__ al_d,
                                               const u16* __restrict__ h1, const float* __restrict__ b1,
                                               const float* __restrict__ W2,
                                               const float* __restrict__ a2s, const float* __restrict__ a2d,
                                               u16* __restrict__ h2b,
                                               float* __restrict__ al_s2, float* __restrict__ al_d2){
    __shared__ float sW2[128 * 32];                  // [k][c], 16 KB
    __shared__ float sh1[4][128];                    // per-wave row strip, 2 KB
    int t = threadIdx.x;
    for (int i = t; i < 128 * 32; i += 256) sW2[i] = W2[i];
    __syncthreads();                                 // start-of-kernel only: no degree coupling
    int wave = t >> 6, lane = t & 63;
    int n = blockIdx.x * 4 + wave;                   // 25000*4 = NN exact
    int start = offsets[n], end = offsets[n + 1];
    int degr = end - start - 1;
    int g = lane >> 4, l = lane & 15, hq = l >> 2;   // channels 8l..8l+7, head = l>>2
    float aldh = al_d[n * 4 + hq];
    const u32x4* h1v = (const u32x4*)h1;             // 16 u32x4 per row
    float acc[8];
    #pragma unroll
    for (int k = 0; k < 8; k++) acc[k] = 0.f;
    float z = 0.f, sa = 0.f;
    // 3-deep pipeline: src 2 ahead, payload 1 ahead
    int i = start + 1 + g;
    int i1 = i + 4, i2 = i + 8;
    int src0 = (i  < end) ? __builtin_nontemporal_load(src32 + i)  : n;
    int src1 = (i1 < end) ? __builtin_nontemporal_load(src32 + i1) : n;
    float a0   = (i < end) ? bf2f(__builtin_nontemporal_load(ale1u + (size_t)i * 4 + hq)) : 0.f;
    float als0 = al_s[src0 * 4 + hq];
    u32x4 v0 = h1v[(size_t)src0 * 16 + l];
    while (i < end){
        int src2 = (i2 < end) ? __builtin_nontemporal_load(src32 + i2) : n;
        float a1v  = (i1 < end) ? bf2f(__builtin_nontemporal_load(ale1u + (size_t)i1 * 4 + hq)) : 0.f;
        float als1 = al_s[src1 * 4 + hq];
        u32x4 v1 = h1v[(size_t)src1 * 16 + l];
        float e = __expf(lreluf(als0 + aldh + a0));
        z += e; sa += a0;
        #pragma unroll
        for (int k = 0; k < 4; k++){
            acc[2 * k]     += e * bf2f((u16)(v0[k] & 0xFFFFu));
            acc[2 * k + 1] += e * bf2f((u16)(v0[k] >> 16));
        }
        i = i1; i1 = i2; i2 += 4;
        src1 = src2; a0 = a1v; als0 = als1; v0 = v1;
    }
    z += __shfl_xor(z, 16); z += __shfl_xor(z, 32);
    sa += __shfl_xor(sa, 16); sa += __shfl_xor(sa, 32);
    float inv_deg = 1.f / fmaxf((float)degr, 1.f);
    float ps = __expf(lreluf(al_s[n * 4 + hq] + aldh + sa * inv_deg));
    z += ps;
    if (g == 0){                                     // self contribution, counted once
        u32x4 v = h1v[(size_t)n * 16 + l];
        #pragma unroll
        for (int k = 0; k < 4; k++){
            acc[2 * k]     += ps * bf2f((u16)(v[k] & 0xFFFFu));
            acc[2 * k + 1] += ps * bf2f((u16)(v[k] >> 16));
        }
    }
    #pragma unroll
    for (int k = 0; k < 8; k++){
        acc[k] += __shfl_xor(acc[k], 16);
        acc[k] += __shfl_xor(acc[k], 32);
    }
    // all lanes now hold the full sum for channels 8l..8l+7 (4x duplicated)
    float rz = 1.f / z;
    if (lane < 16){                                  // stage fp32 row (post bias+ELU) to this wave's strip
        f32x4 w0, w1;
        #pragma unroll
        for (int k = 0; k < 4; k++){
            w0[k] = eluf(acc[k]     * rz + b1[l * 8 + k]);
            w1[k] = eluf(acc[4 + k] * rz + b1[l * 8 + 4 + k]);
        }
        f32x4* dstp = (f32x4*)&sh1[wave][l * 8];
        dstp[0] = w0; dstp[1] = w1;
    }
    // wave-local LDS ordering (lgkmcnt) makes the strip visible without a barrier
    int c = lane & 31, half = lane >> 5;             // col c; halves split K
    const float* hr = sh1[wave] + half * 64;
    const float* wc = &sW2[half * 64 * 32 + c];
    float s = 0.f;
    #pragma unroll
    for (int j = 0; j < 64; j += 4){
        f32x4 rv = *(const f32x4*)(hr + j);          // broadcast within half
        s += rv[0] * wc[(j + 0) * 32] + rv[1] * wc[(j + 1) * 32]
           + rv[2] * wc[(j + 2) * 32] + rv[3] * wc[(j + 3) * 32];
    }
    s += __shfl_xor(s, 32);                          // combine K-halves
    if (half == 0) h2b[(size_t)n * 32 + c] = f2bf(s);
    float vs = s * a2s[c], vd = s * a2d[c];
    #pragma unroll
    for (int m = 1; m < 32; m <<= 1){ vs += __shfl_xor(vs, m); vd += __shfl_xor(vd, m); }
    if (lane == 0){ al_s2[n] = vs; al_d2[n] = vd; }
}

// ================= layer 2: FUSED softmax + aggregate (bf16 h2b gather, 3-deep pipeline) =================
__global__ __launch_bounds__(256) void k_node2(const int* __restrict__ src32, const u16* __restrict__ ale2p,
                                               const int* __restrict__ offsets,
                                               const float* __restrict__ al_s, const float* __restrict__ al_d,
                                               const u16* __restrict__ h2b, const float* __restrict__ b2,
                                               float* __restrict__ dout, float* __restrict__ rzv){
    int wave = threadIdx.x >> 6, lane = threadIdx.x & 63;
    int n = blockIdx.x * 4 + wave;
    int start = offsets[n], end = offsets[n + 1];
    int degr = end - start - 1;
    float aldn = al_d[n];
    int g = lane >> 3, l = lane & 7;                 // 8 edges in flight, channels l*4..l*4+3
    const uint2* h2v = (const uint2*)h2b;            // 8 uint2 (4 bf16 each) per row
    f32x4 acc = (f32x4){0.f, 0.f, 0.f, 0.f};
    float z = 0.f, sa = 0.f;
    int i = start + 1 + g;
    int i1 = i + 8, i2 = i + 16;
    int src0 = (i  < end) ? __builtin_nontemporal_load(src32 + i)  : n;
    int src1 = (i1 < end) ? __builtin_nontemporal_load(src32 + i1) : n;
    float a0   = (i < end) ? bf2f(__builtin_nontemporal_load(ale2p + i)) : 0.f;
    float als0 = al_s[src0];
    uint2 v0 = h2v[(size_t)src0 * 8 + l];
    while (i < end){
        int src2 = (i2 < end) ? __builtin_nontemporal_load(src32 + i2) : n;
        float a1v  = (i1 < end) ? bf2f(__builtin_nontemporal_load(ale2p + i1)) : 0.f;
        float als1 = al_s[src1];
        uint2 v1 = h2v[(size_t)src1 * 8 + l];
        float e = __expf(lreluf(als0 + aldn + a0));
        z += e; sa += a0;
        acc[0] += e * bf2f((u16)(v0.x & 0xFFFFu));
        acc[1] += e * bf2f((u16)(v0.x >> 16));
        acc[2] += e * bf2f((u16)(v0.y & 0xFFFFu));
        acc[3] += e * bf2f((u16)(v0.y >> 16));
        i = i1; i1 = i2; i2 += 8;
        src1 = src2; a0 = a1v; als0 = als1; v0 = v1;
    }
    z += __shfl_xor(z, 8); z += __shfl_xor(z, 16); z += __shfl_xor(z, 32);
    sa += __shfl_xor(sa, 8); sa += __shfl_xor(sa, 16); sa += __shfl_xor(sa, 32);
    float mal = sa / fmaxf((float)degr, 1.f);
    float ps = __expf(lreluf(al_s[n] + aldn + mal));
    z += ps;
    float rz = 1.f / z;
    if (g == 0){                                     // self contribution
        uint2 v = h2v[(size_t)n * 8 + l];
        acc[0] += ps * bf2f((u16)(v.x & 0xFFFFu));
        acc[1] += ps * bf2f((u16)(v.x >> 16));
        acc[2] += ps * bf2f((u16)(v.y & 0xFFFFu));
        acc[3] += ps * bf2f((u16)(v.y >> 16));
    }
    if (lane == 0){
        rzv[n] = rz;
        dout[OUT_AL + NE + n] = ps * rz;             // self-loop alpha
        dout[OUT_EI + NE + n] = (float)n;            // self-loop edge_index entries
        dout[OUT_EI + NE2 + NE + n] = (float)n;
    }
    #pragma unroll
    for (int k = 0; k < 4; k++){
        acc[k] += __shfl_xor(acc[k], 8);
        acc[k] += __shfl_xor(acc[k], 16);
        acc[k] += __shfl_xor(acc[k], 32);
    }
    if (g == 0){
        f32x4 w;
        #pragma unroll
        for (int k = 0; k < 4; k++) w[k] = eluf(acc[k] * rz + b2[l * 4 + k]);
        ((f32x4*)dout)[(size_t)n * 8 + l] = w;
    }
}

// alpha + edge_index for real edges, original edge order: all writes sequential
__global__ __launch_bounds__(256) void k_alpha(const int* __restrict__ ei, const u16* __restrict__ ale2,
                                               const float* __restrict__ al_s, const float* __restrict__ al_d,
                                               const float* __restrict__ rzv, float* __restrict__ dout){
    int e = blockIdx.x * 256 + threadIdx.x;          // NE exact
    int src = ei[e], dst = ei[NE + e];
    float a = bf2f(ale2[e]);
    float ev = __expf(lreluf(al_s[src] + al_d[dst] + a));
    __builtin_nontemporal_store(ev * rzv[dst], &dout[OUT_AL + e]);
    __builtin_nontemporal_store((float)src, &dout[OUT_EI + e]);
    __builtin_nontemporal_store((float)dst, &dout[OUT_EI + NE2 + e]);
}

extern "C" void kernel_launch(void* const* d_in, const int* in_sizes, int n_in,
                              void* d_out, int out_size, void* d_ws, size_t ws_size,
                              hipStream_t stream) {
    const float* x     = (const float*)d_in[0];
    const int*   ei    = (const int*)d_in[1];
    const float* eattr = (const float*)d_in[2];
    const float* W1    = (const float*)d_in[3];
    const float* W1e   = (const float*)d_in[4];
    const float* a1s   = (const float*)d_in[5];
    const float* a1d   = (const float*)d_in[6];
    const float* a1e   = (const float*)d_in[7];
    const float* b1    = (const float*)d_in[8];
    const float* W2    = (const float*)d_in[9];
    const float* W2e   = (const float*)d_in[10];
    const float* a2s   = (const float*)d_in[11];
    const float* a2d   = (const float*)d_in[12];
    const float* a2e   = (const float*)d_in[13];
    const float* b2    = (const float*)d_in[14];
    float* dout = (float*)d_out;

    char* ws = (char*)d_ws;
    size_t off = 0;
    auto alloc = [&](size_t bytes) -> void* {
        void* p = ws + off;
        off += (bytes + 255) & ~(size_t)255;
        return p;
    };
    // --- zero-initialized: bucket counters only ---
    int* bcnt = (int*)alloc((size_t)NB * 4);
    size_t zero_bytes = off;
    // --- rest fully written before read ---
    int*     offsets = (int*)alloc((size_t)(NN + 1) * 4);
    u32*     binsP   = (u32*)alloc((size_t)NB * CAP * 4);    // dead after k_fscatter
    uint2*   binsA   = (uint2*)alloc((size_t)NB * CAP * 8);  // dead after k_fscatter
    u16*     binsA2  = (u16*)alloc((size_t)NB * CAP * 2);    // dead after k_fscatter
    int*     src32   = (int*)alloc((size_t)NE2 * 4);
    uint2*   ale1p   = (uint2*)alloc((size_t)NE2 * 8);
    u16*     ale2p   = (u16*)alloc((size_t)NE2 * 2);
    u16*     ale1    = (u16*)alloc((size_t)NE * 4 * 2);      // dead after k_bscatter
    u16*     ale2    = (u16*)alloc((size_t)NE * 2);          // live until k_alpha
    float*   al_s1   = (float*)alloc((size_t)NN * 4 * 4);
    float*   al_d1   = (float*)alloc((size_t)NN * 4 * 4);
    u16*     h1      = (u16*)alloc((size_t)NN * 128 * 2);    // live until k_node1 done
    // aliases into bin regions (dead after k_fscatter; written by k_node1/k_node2)
    u16*   h2b   = (u16*)binsP;                              // NN*32*2 = 6.4 MB in 8.0 MB
    float* al_s2 = (float*)binsA;                            // 3*NNP*4 = 1.2 MB in 16 MB
    float* al_d2 = al_s2 + NNP;
    float* rzv   = al_d2 + NNP;

    const int TB = 256;
    hipMemsetAsync(d_ws, 0, zero_bytes, stream);

    // edge logits
    k_ale<<<NE * 4 / TB, TB, 0, stream>>>(eattr, W1e, a1e, W2e, a2e, ale1, ale2);
    // bucketed CSR build
    k_bscatter<<<NBB, TB, 0, stream>>>(ei, ale1, ale2, bcnt, binsP, binsA, binsA2);
    k_fscatter<<<NB, TB, 0, stream>>>(binsP, binsA, binsA2, bcnt, offsets, src32, ale1p, ale2p);
    // layer 1 (al1 fused into gemm1; gemm2+al2 fused wave-locally into node1)
    k_gemm1<<<(NN + 63) / 64, TB, 0, stream>>>(x, W1, a1s, a1d, h1, al_s1, al_d1);
    k_node1<<<NN / 4, TB, 0, stream>>>(src32, (const u16*)ale1p, offsets, al_s1, al_d1, h1, b1,
                                       W2, a2s, a2d, h2b, al_s2, al_d2);
    // layer 2
    k_node2<<<NN / 4, TB, 0, stream>>>(src32, ale2p, offsets, al_s2, al_d2, h2b, b2, dout, rzv);
    k_alpha<<<NE / TB, TB, 0, stream>>>(ei, ale2, al_s2, al_d2, rzv, dout);
}

// Round 7
// 591.501 us; speedup vs baseline: 1.0640x; 1.0640x over previous
//
#include <hip/hip_runtime.h>

#define NN 100000
#define NE 1600000
#define NE2 1700000
#define OUT_EI 3200000
#define OUT_AL 6600000
#define SLOPE 0.2f
#define NB 391       // ceil(NN/256): dst buckets (256 nodes each)
#define EPB 6400     // edges per block in binning kernel
#define NBB 250      // NE / EPB
#define CAP 5120     // fixed bucket capacity (mean 4096, sigma 64 -> 16 sigma margin)
#define NNP 100096   // NN padded for aliased sub-buffers

typedef unsigned short u16;
typedef unsigned int u32;
typedef __bf16 bf16x8 __attribute__((ext_vector_type(8)));
typedef float f32x4 __attribute__((ext_vector_type(4)));
typedef u32 u32x4 __attribute__((ext_vector_type(4)));

__device__ __forceinline__ float bf2f(u16 u){ return __uint_as_float(((u32)u) << 16); }
__device__ __forceinline__ u16 f2bf(float f){
    u32 x = __float_as_uint(f);
    x += 0x7FFFu + ((x >> 16) & 1u);   // round-to-nearest-even
    return (u16)(x >> 16);
}
__device__ __forceinline__ float eluf(float v){ return v > 0.f ? v : (__expf(v) - 1.f); }
__device__ __forceinline__ float lreluf(float v){ return fmaxf(v, SLOPE * v); }
__device__ __forceinline__ float sel4f(float a, float b, float c, float d, int s){
    float x = (s & 1) ? b : a;
    float y = (s & 1) ? d : c;
    return (s & 2) ? y : x;
}

// ================= edge logits precompute =================
__global__ __launch_bounds__(256) void k_ale(const float* __restrict__ eattr,
                                             const float* __restrict__ W1e, const float* __restrict__ a1e,
                                             const float* __restrict__ W2e, const float* __restrict__ a2e,
                                             u16* __restrict__ ale1, u16* __restrict__ ale2){
    __shared__ float sq1[64], sq2[16];
    int t = threadIdx.x;
    if (t < 64){
        int k = t >> 2, h = t & 3;
        float s = 0.f;
        #pragma unroll 8
        for (int c = 0; c < 32; c++) s += W1e[k * 128 + h * 32 + c] * a1e[h * 32 + c];
        sq1[t] = s;
    }
    if (t < 16){
        float s2 = 0.f;
        #pragma unroll 8
        for (int c = 0; c < 32; c++) s2 += W2e[t * 32 + c] * a2e[c];
        sq2[t] = s2;
    }
    __syncthreads();
    int gt = blockIdx.x * 256 + t;                   // NE*4 exact
    int e = gt >> 2, part = gt & 3;
    f32x4 av = ((const f32x4*)eattr)[(size_t)e * 4 + part];
    int j0 = part * 4;
    float p0 = 0, p1 = 0, p2 = 0, p3 = 0, p4 = 0;
    #pragma unroll
    for (int k = 0; k < 4; k++){
        float a = av[k]; int j = j0 + k;
        p0 += a * sq1[j * 4 + 0]; p1 += a * sq1[j * 4 + 1];
        p2 += a * sq1[j * 4 + 2]; p3 += a * sq1[j * 4 + 3];
        p4 += a * sq2[j];
    }
    #pragma unroll
    for (int m = 1; m < 4; m <<= 1){
        p0 += __shfl_xor(p0, m); p1 += __shfl_xor(p1, m);
        p2 += __shfl_xor(p2, m); p3 += __shfl_xor(p3, m); p4 += __shfl_xor(p4, m);
    }
    if (part == 0){
        ushort4 w; w.x = f2bf(p0); w.y = f2bf(p1); w.z = f2bf(p2); w.w = f2bf(p3);
        ((ushort4*)ale1)[e] = w;
        ale2[e] = f2bf(p4);
    }
}

// ================= bucketed CSR build (fixed-capacity buckets) =================
__global__ __launch_bounds__(256) void k_bscatter(const int* __restrict__ ei, const u16* __restrict__ ale1,
                                                  const u16* __restrict__ ale2,
                                                  int* __restrict__ bcnt, u32* __restrict__ binsP,
                                                  uint2* __restrict__ binsA, u16* __restrict__ binsA2){
    __shared__ int cnt[NB];
    __shared__ int base[NB];
    __shared__ int sdst[EPB];
    int t = threadIdx.x;
    for (int i = t; i < NB; i += 256) cnt[i] = 0;
    __syncthreads();
    int e0 = blockIdx.x * EPB;
    for (int i = t; i < EPB; i += 256){
        int dv = ei[NE + e0 + i];
        sdst[i] = dv;
        atomicAdd(&cnt[dv >> 8], 1);
    }
    __syncthreads();
    for (int i = t; i < NB; i += 256){
        int c = cnt[i];
        base[i] = c ? atomicAdd(&bcnt[i], c) : 0;    // bcnt ends as per-bucket totals
        cnt[i] = 0;
    }
    __syncthreads();
    const uint2* a1 = (const uint2*)ale1;
    for (int i = t; i < EPB; i += 256){
        int e = e0 + i;
        int dst = sdst[i];
        int b = dst >> 8;
        int r = base[b] + atomicAdd(&cnt[b], 1);
        if (r < CAP){                                // 16-sigma guard (never taken for this data)
            size_t pos = (size_t)b * CAP + r;
            binsP[pos] = ((u32)(dst & 255) << 24) | (u32)ei[e];
            binsA[pos] = a1[e];
            binsA2[pos] = ale2[e];
        }
    }
}

// per-bucket: cross-bucket prefix + degree hist + node scan -> offsets + fine scatter
__global__ __launch_bounds__(256) void k_fscatter(const u32* __restrict__ binsP, const uint2* __restrict__ binsA,
                                                  const u16* __restrict__ binsA2, const int* __restrict__ bcnt,
                                                  int* __restrict__ offsets,
                                                  int* __restrict__ src32, uint2* __restrict__ ale1p,
                                                  u16* __restrict__ ale2p){
    __shared__ int sc[512];
    __shared__ int d[256];
    __shared__ int s[256];
    __shared__ int cur[256];
    int t = threadIdx.x, b = blockIdx.x;
    int v0 = (t < NB) ? bcnt[t] : 0;
    int v1 = (t + 256 < NB) ? bcnt[t + 256] : 0;
    sc[t] = v0; sc[t + 256] = v1;
    d[t] = 0;
    __syncthreads();
    #pragma unroll
    for (int dd = 1; dd < 512; dd <<= 1){
        int x0 = (t >= dd) ? sc[t - dd] : 0;
        int x1 = (t + 256 >= dd) ? sc[t + 256 - dd] : 0;
        __syncthreads();
        sc[t] += x0; sc[t + 256] += x1;
        __syncthreads();
    }
    int myCnt = bcnt[b];
    int myBase = sc[b] - myCnt;                      // exclusive prefix of bucket b
    size_t bb = (size_t)b * CAP;
    for (int i = t; i < myCnt; i += 256)
        atomicAdd(&d[binsP[bb + i] >> 24], 1);
    __syncthreads();
    int dv = d[t];
    s[t] = dv; __syncthreads();
    #pragma unroll
    for (int dd = 1; dd < 256; dd <<= 1){
        int x = (t >= dd) ? s[t - dd] : 0;
        __syncthreads();
        s[t] += x;
        __syncthreads();
    }
    int n = b * 256 + t;
    int off = myBase + (s[t] - dv) + n;              // + n: one self-loop slot per preceding node
    if (n < NN) offsets[n] = off;
    cur[t] = off + 1;                                // real edges start after self-loop slot
    if (b == 0 && t == 0) offsets[NN] = NE + NN;
    __syncthreads();
    for (int i = t; i < myCnt; i += 256){
        u32 p = binsP[bb + i];
        int pos = atomicAdd(&cur[p >> 24], 1);
        src32[pos] = (int)(p & 0xFFFFFFu);
        ale1p[pos] = binsA[bb + i];
        ale2p[pos] = binsA2[bb + i];
    }
}

// ================= GEMM 1 (with fused al_s1/al_d1 epilogue) =================
__global__ __launch_bounds__(256) void k_gemm1(const float* __restrict__ x, const float* __restrict__ W,
                                               const float* __restrict__ a1s, const float* __restrict__ a1d,
                                               u16* __restrict__ h1,
                                               float* __restrict__ al_s, float* __restrict__ al_d){
    __shared__ __align__(16) u16 sW[128 * 136];      // transposed: sW[col*136+k]
    int t = threadIdx.x;
    for (int i = t; i < 128 * 128; i += 256){
        int k = i >> 7, c = i & 127;
        sW[c * 136 + k] = f2bf(W[i]);
    }
    __syncthreads();
    int lane = t & 63, wave = t >> 6;
    int quad = lane >> 4, m16 = lane & 15;
    int rowA = blockIdx.x * 64 + wave * 16 + m16;
    bf16x8 afr[4];
    if (rowA < NN){
        const f32x4* xr = (const f32x4*)(x + (size_t)rowA * 128);
        #pragma unroll
        for (int kk = 0; kk < 4; kk++){
            f32x4 va = xr[kk * 8 + quad * 2];
            f32x4 vb = xr[kk * 8 + quad * 2 + 1];
            #pragma unroll
            for (int i2 = 0; i2 < 4; i2++){ afr[kk][i2] = (__bf16)va[i2]; afr[kk][4 + i2] = (__bf16)vb[i2]; }
        }
    } else {
        #pragma unroll
        for (int kk = 0; kk < 4; kk++)
            #pragma unroll
            for (int i2 = 0; i2 < 8; i2++) afr[kk][i2] = (__bf16)0.f;
    }
    int rowbase = blockIdx.x * 64 + wave * 16 + quad * 4;
    float vsA[4][4], vdA[4][4];
    #pragma unroll
    for (int r = 0; r < 4; r++)
        #pragma unroll
        for (int h = 0; h < 4; h++){ vsA[r][h] = 0.f; vdA[r][h] = 0.f; }
    #pragma unroll
    for (int nt = 0; nt < 8; nt++){
        f32x4 acc = (f32x4){0.f, 0.f, 0.f, 0.f};
        const u16* wp = &sW[(nt * 16 + m16) * 136 + quad * 8];
        #pragma unroll
        for (int kk = 0; kk < 4; kk++){
            bf16x8 bfr = *(const bf16x8*)(wp + kk * 32);
            acc = __builtin_amdgcn_mfma_f32_16x16x32_bf16(afr[kk], bfr, acc, 0, 0, 0);
        }
        int col = nt * 16 + m16;
        float cs = a1s[col], cd = a1d[col];
        const int h = nt >> 1;                       // head uniform per nt
        #pragma unroll
        for (int r = 0; r < 4; r++){
            vsA[r][h] += acc[r] * cs;
            vdA[r][h] += acc[r] * cd;
            int row = rowbase + r;
            if (row < NN) h1[(size_t)row * 128 + col] = f2bf(acc[r]);
        }
    }
    #pragma unroll
    for (int r = 0; r < 4; r++)
        #pragma unroll
        for (int h = 0; h < 4; h++)
            #pragma unroll
            for (int m = 1; m < 16; m <<= 1){
                vsA[r][h] += __shfl_xor(vsA[r][h], m);
                vdA[r][h] += __shfl_xor(vdA[r][h], m);
            }
    int rs = m16 >> 2, hs = m16 & 3;                 // lane m16 writes (row rs, head hs)
    float s0 = sel4f(vsA[0][0], vsA[0][1], vsA[0][2], vsA[0][3], hs);
    float s1 = sel4f(vsA[1][0], vsA[1][1], vsA[1][2], vsA[1][3], hs);
    float s2 = sel4f(vsA[2][0], vsA[2][1], vsA[2][2], vsA[2][3], hs);
    float s3 = sel4f(vsA[3][0], vsA[3][1], vsA[3][2], vsA[3][3], hs);
    float d0 = sel4f(vdA[0][0], vdA[0][1], vdA[0][2], vdA[0][3], hs);
    float d1 = sel4f(vdA[1][0], vdA[1][1], vdA[1][2], vdA[1][3], hs);
    float d2 = sel4f(vdA[2][0], vdA[2][1], vdA[2][2], vdA[2][3], hs);
    float d3 = sel4f(vdA[3][0], vdA[3][1], vdA[3][2], vdA[3][3], hs);
    float souts = sel4f(s0, s1, s2, s3, rs);
    float soutd = sel4f(d0, d1, d2, d3, rs);
    int row = rowbase + rs;
    if (row < NN){
        al_s[row * 4 + hs] = souts;
        al_d[row * 4 + hs] = soutd;
    }
}

// ================= layer 1: FUSED softmax + aggregate, barrier-free, 3-deep pipeline =================
// 16-lane groups, 4 edges in flight, wave-per-node (round-5 structure, measured 98 us).
__global__ __launch_bounds__(256) void k_node1(const int* __restrict__ src32, const u16* __restrict__ ale1u,
                                               const int* __restrict__ offsets,
                                               const float* __restrict__ al_s, const float* __restrict__ al_d,
                                               const u16* __restrict__ h1, const float* __restrict__ b1,
                                               u16* __restrict__ h1b){
    int wave = threadIdx.x >> 6, lane = threadIdx.x & 63;
    int n = blockIdx.x * 4 + wave;               // 25000*4 = NN exact
    int start = offsets[n], end = offsets[n + 1];
    int degr = end - start - 1;
    int g = lane >> 4, l = lane & 15, hq = l >> 2;   // channels 8l..8l+7, head = l>>2
    float aldh = al_d[n * 4 + hq];
    const u32x4* h1v = (const u32x4*)h1;             // 16 u32x4 per row
    float acc[8];
    #pragma unroll
    for (int k = 0; k < 8; k++) acc[k] = 0.f;
    float z = 0.f, sa = 0.f;
    // 3-deep pipeline: src 2 ahead, payload 1 ahead
    int i = start + 1 + g;
    int i1 = i + 4, i2 = i + 8;
    int src0 = (i  < end) ? __builtin_nontemporal_load(src32 + i)  : n;
    int src1 = (i1 < end) ? __builtin_nontemporal_load(src32 + i1) : n;
    float a0   = (i < end) ? bf2f(__builtin_nontemporal_load(ale1u + (size_t)i * 4 + hq)) : 0.f;
    float als0 = al_s[src0 * 4 + hq];
    u32x4 v0 = h1v[(size_t)src0 * 16 + l];
    while (i < end){
        int src2 = (i2 < end) ? __builtin_nontemporal_load(src32 + i2) : n;
        float a1v  = (i1 < end) ? bf2f(__builtin_nontemporal_load(ale1u + (size_t)i1 * 4 + hq)) : 0.f;
        float als1 = al_s[src1 * 4 + hq];
        u32x4 v1 = h1v[(size_t)src1 * 16 + l];
        float e = __expf(lreluf(als0 + aldh + a0));
        z += e; sa += a0;
        #pragma unroll
        for (int k = 0; k < 4; k++){
            acc[2 * k]     += e * bf2f((u16)(v0[k] & 0xFFFFu));
            acc[2 * k + 1] += e * bf2f((u16)(v0[k] >> 16));
        }
        i = i1; i1 = i2; i2 += 4;
        src1 = src2; a0 = a1v; als0 = als1; v0 = v1;
    }
    // reduce z/sa across the 4 groups
    z += __shfl_xor(z, 16); z += __shfl_xor(z, 32);
    sa += __shfl_xor(sa, 16); sa += __shfl_xor(sa, 32);
    float inv_deg = 1.f / fmaxf((float)degr, 1.f);
    float ps = __expf(lreluf(al_s[n * 4 + hq] + aldh + sa * inv_deg));
    z += ps;
    if (g == 0){                                     // self contribution, counted once
        u32x4 v = h1v[(size_t)n * 16 + l];
        #pragma unroll
        for (int k = 0; k < 4; k++){
            acc[2 * k]     += ps * bf2f((u16)(v[k] & 0xFFFFu));
            acc[2 * k + 1] += ps * bf2f((u16)(v[k] >> 16));
        }
    }
    #pragma unroll
    for (int k = 0; k < 8; k++){
        acc[k] += __shfl_xor(acc[k], 16);
        acc[k] += __shfl_xor(acc[k], 32);
    }
    if (g == 0){
        float rz = 1.f / z;
        u32x4 w;
        #pragma unroll
        for (int k = 0; k < 4; k++){
            float v0e = eluf(acc[2 * k]     * rz + b1[l * 8 + 2 * k]);
            float v1e = eluf(acc[2 * k + 1] * rz + b1[l * 8 + 2 * k + 1]);
            w[k] = (u32)f2bf(v0e) | ((u32)f2bf(v1e) << 16);
        }
        ((u32x4*)h1b)[(size_t)n * 16 + l] = w;
    }
}

// ================= GEMM 2 (bf16 h2b output + fused al_s2/al_d2 epilogue) =================
__global__ __launch_bounds__(256) void k_gemm2(const u16* __restrict__ hin, const float* __restrict__ W,
                                               const float* __restrict__ a2s, const float* __restrict__ a2d,
                                               u16* __restrict__ h2b,
                                               float* __restrict__ al_s, float* __restrict__ al_d){
    __shared__ __align__(16) u16 sW[32 * 136];
    int t = threadIdx.x;
    for (int i = t; i < 128 * 32; i += 256){
        int k = i >> 5, c = i & 31;
        sW[c * 136 + k] = f2bf(W[i]);
    }
    __syncthreads();
    int lane = t & 63, wave = t >> 6;
    int quad = lane >> 4, m16 = lane & 15;
    int rowA = blockIdx.x * 64 + wave * 16 + m16;
    bf16x8 afr[4];
    if (rowA < NN){
        const u16* xr = hin + (size_t)rowA * 128 + quad * 8;
        #pragma unroll
        for (int kk = 0; kk < 4; kk++) afr[kk] = *(const bf16x8*)(xr + kk * 32);
    } else {
        #pragma unroll
        for (int kk = 0; kk < 4; kk++)
            #pragma unroll
            for (int i2 = 0; i2 < 8; i2++) afr[kk][i2] = (__bf16)0.f;
    }
    int rowbase = blockIdx.x * 64 + wave * 16 + quad * 4;
    float vs2[4], vd2[4];
    #pragma unroll
    for (int r = 0; r < 4; r++){ vs2[r] = 0.f; vd2[r] = 0.f; }
    #pragma unroll
    for (int nt = 0; nt < 2; nt++){
        f32x4 acc = (f32x4){0.f, 0.f, 0.f, 0.f};
        const u16* wp = &sW[(nt * 16 + m16) * 136 + quad * 8];
        #pragma unroll
        for (int kk = 0; kk < 4; kk++){
            bf16x8 bfr = *(const bf16x8*)(wp + kk * 32);
            acc = __builtin_amdgcn_mfma_f32_16x16x32_bf16(afr[kk], bfr, acc, 0, 0, 0);
        }
        int col = nt * 16 + m16;
        float cs = a2s[col], cd = a2d[col];
        #pragma unroll
        for (int r = 0; r < 4; r++){
            vs2[r] += acc[r] * cs;
            vd2[r] += acc[r] * cd;
            int row = rowbase + r;
            if (row < NN) h2b[(size_t)row * 32 + col] = f2bf(acc[r]);
        }
    }
    #pragma unroll
    for (int r = 0; r < 4; r++)
        #pragma unroll
        for (int m = 1; m < 16; m <<= 1){
            vs2[r] += __shfl_xor(vs2[r], m);
            vd2[r] += __shfl_xor(vd2[r], m);
        }
    if (m16 < 4){
        int row = rowbase + m16;
        if (row < NN){
            al_s[row] = sel4f(vs2[0], vs2[1], vs2[2], vs2[3], m16);
            al_d[row] = sel4f(vd2[0], vd2[1], vd2[2], vd2[3], m16);
        }
    }
}

// ================= layer 2: FUSED softmax + aggregate (bf16 h2b gather, 3-deep pipeline) =================
__global__ __launch_bounds__(256) void k_node2(const int* __restrict__ src32, const u16* __restrict__ ale2p,
                                               const int* __restrict__ offsets,
                                               const float* __restrict__ al_s, const float* __restrict__ al_d,
                                               const u16* __restrict__ h2b, const float* __restrict__ b2,
                                               float* __restrict__ dout, float* __restrict__ rzv){
    int wave = threadIdx.x >> 6, lane = threadIdx.x & 63;
    int n = blockIdx.x * 4 + wave;
    int start = offsets[n], end = offsets[n + 1];
    int degr = end - start - 1;
    float aldn = al_d[n];
    int g = lane >> 3, l = lane & 7;                 // 8 edges in flight, channels l*4..l*4+3
    const uint2* h2v = (const uint2*)h2b;            // 8 uint2 (4 bf16 each) per row
    f32x4 acc = (f32x4){0.f, 0.f, 0.f, 0.f};
    float z = 0.f, sa = 0.f;
    int i = start + 1 + g;
    int i1 = i + 8, i2 = i + 16;
    int src0 = (i  < end) ? __builtin_nontemporal_load(src32 + i)  : n;
    int src1 = (i1 < end) ? __builtin_nontemporal_load(src32 + i1) : n;
    float a0   = (i < end) ? bf2f(__builtin_nontemporal_load(ale2p + i)) : 0.f;
    float als0 = al_s[src0];
    uint2 v0 = h2v[(size_t)src0 * 8 + l];
    while (i < end){
        int src2 = (i2 < end) ? __builtin_nontemporal_load(src32 + i2) : n;
        float a1v  = (i1 < end) ? bf2f(__builtin_nontemporal_load(ale2p + i1)) : 0.f;
        float als1 = al_s[src1];
        uint2 v1 = h2v[(size_t)src1 * 8 + l];
        float e = __expf(lreluf(als0 + aldn + a0));
        z += e; sa += a0;
        acc[0] += e * bf2f((u16)(v0.x & 0xFFFFu));
        acc[1] += e * bf2f((u16)(v0.x >> 16));
        acc[2] += e * bf2f((u16)(v0.y & 0xFFFFu));
        acc[3] += e * bf2f((u16)(v0.y >> 16));
        i = i1; i1 = i2; i2 += 8;
        src1 = src2; a0 = a1v; als0 = als1; v0 = v1;
    }
    z += __shfl_xor(z, 8); z += __shfl_xor(z, 16); z += __shfl_xor(z, 32);
    sa += __shfl_xor(sa, 8); sa += __shfl_xor(sa, 16); sa += __shfl_xor(sa, 32);
    float mal = sa / fmaxf((float)degr, 1.f);
    float ps = __expf(lreluf(al_s[n] + aldn + mal));
    z += ps;
    float rz = 1.f / z;
    if (g == 0){                                     // self contribution
        uint2 v = h2v[(size_t)n * 8 + l];
        acc[0] += ps * bf2f((u16)(v.x & 0xFFFFu));
        acc[1] += ps * bf2f((u16)(v.x >> 16));
        acc[2] += ps * bf2f((u16)(v.y & 0xFFFFu));
        acc[3] += ps * bf2f((u16)(v.y >> 16));
    }
    if (lane == 0){
        rzv[n] = rz;
        dout[OUT_AL + NE + n] = ps * rz;             // self-loop alpha
        dout[OUT_EI + NE + n] = (float)n;            // self-loop edge_index entries
        dout[OUT_EI + NE2 + NE + n] = (float)n;
    }
    #pragma unroll
    for (int k = 0; k < 4; k++){
        acc[k] += __shfl_xor(acc[k], 8);
        acc[k] += __shfl_xor(acc[k], 16);
        acc[k] += __shfl_xor(acc[k], 32);
    }
    if (g == 0){
        f32x4 w;
        #pragma unroll
        for (int k = 0; k < 4; k++) w[k] = eluf(acc[k] * rz + b2[l * 4 + k]);
        ((f32x4*)dout)[(size_t)n * 8 + l] = w;
    }
}

// alpha + edge_index for real edges, original edge order: all writes sequential
__global__ __launch_bounds__(256) void k_alpha(const int* __restrict__ ei, const u16* __restrict__ ale2,
                                               const float* __restrict__ al_s, const float* __restrict__ al_d,
                                               const float* __restrict__ rzv, float* __restrict__ dout){
    int e = blockIdx.x * 256 + threadIdx.x;          // NE exact
    int src = ei[e], dst = ei[NE + e];
    float a = bf2f(ale2[e]);
    float ev = __expf(lreluf(al_s[src] + al_d[dst] + a));
    __builtin_nontemporal_store(ev * rzv[dst], &dout[OUT_AL + e]);
    __builtin_nontemporal_store((float)src, &dout[OUT_EI + e]);
    __builtin_nontemporal_store((float)dst, &dout[OUT_EI + NE2 + e]);
}

extern "C" void kernel_launch(void* const* d_in, const int* in_sizes, int n_in,
                              void* d_out, int out_size, void* d_ws, size_t ws_size,
                              hipStream_t stream) {
    const float* x     = (const float*)d_in[0];
    const int*   ei    = (const int*)d_in[1];
    const float* eattr = (const float*)d_in[2];
    const float* W1    = (const float*)d_in[3];
    const float* W1e   = (const float*)d_in[4];
    const float* a1s   = (const float*)d_in[5];
    const float* a1d   = (const float*)d_in[6];
    const float* a1e   = (const float*)d_in[7];
    const float* b1    = (const float*)d_in[8];
    const float* W2    = (const float*)d_in[9];
    const float* W2e   = (const float*)d_in[10];
    const float* a2s   = (const float*)d_in[11];
    const float* a2d   = (const float*)d_in[12];
    const float* a2e   = (const float*)d_in[13];
    const float* b2    = (const float*)d_in[14];
    float* dout = (float*)d_out;

    char* ws = (char*)d_ws;
    size_t off = 0;
    auto alloc = [&](size_t bytes) -> void* {
        void* p = ws + off;
        off += (bytes + 255) & ~(size_t)255;
        return p;
    };
    // --- zero-initialized: bucket counters only ---
    int* bcnt = (int*)alloc((size_t)NB * 4);
    size_t zero_bytes = off;
    // --- rest fully written before read ---
    int*     offsets = (int*)alloc((size_t)(NN + 1) * 4);
    u32*     binsP   = (u32*)alloc((size_t)NB * CAP * 4);    // dead after k_fscatter
    uint2*   binsA   = (uint2*)alloc((size_t)NB * CAP * 8);  // dead after k_fscatter
    u16*     binsA2  = (u16*)alloc((size_t)NB * CAP * 2);    // dead after k_fscatter
    int*     src32   = (int*)alloc((size_t)NE2 * 4);
    uint2*   ale1p   = (uint2*)alloc((size_t)NE2 * 8);
    u16*     ale2p   = (u16*)alloc((size_t)NE2 * 2);
    u16*     ale1    = (u16*)alloc((size_t)NE * 4 * 2);      // dead after k_bscatter
    u16*     ale2    = (u16*)alloc((size_t)NE * 2);          // live until k_alpha
    float*   al_s1   = (float*)alloc((size_t)NN * 4 * 4);
    float*   al_d1   = (float*)alloc((size_t)NN * 4 * 4);
    u16*     h1      = (u16*)alloc((size_t)NN * 128 * 2);    // dead after k_node1
    // aliases into dead regions:
    u16*   h1b   = (u16*)binsP;                              // 25.6 MB in 28 MB bins region (dead after fscatter)
    char*  h1r   = (char*)h1;                                // h1 region reused after k_node1:
    u16*   h2b   = (u16*)h1r;                                //   NN*32*2 = 6.4 MB
    float* al_s2 = (float*)(h1r + 6400000);                  //   NN*4
    float* al_d2 = al_s2 + NNP;
    float* rzv   = al_d2 + NNP;

    const int TB = 256;
    hipMemsetAsync(d_ws, 0, zero_bytes, stream);

    // edge logits
    k_ale<<<NE * 4 / TB, TB, 0, stream>>>(eattr, W1e, a1e, W2e, a2e, ale1, ale2);
    // bucketed CSR build
    k_bscatter<<<NBB, TB, 0, stream>>>(ei, ale1, ale2, bcnt, binsP, binsA, binsA2);
    k_fscatter<<<NB, TB, 0, stream>>>(binsP, binsA, binsA2, bcnt, offsets, src32, ale1p, ale2p);
    // layer 1
    k_gemm1<<<(NN + 63) / 64, TB, 0, stream>>>(x, W1, a1s, a1d, h1, al_s1, al_d1);
    k_node1<<<NN / 4, TB, 0, stream>>>(src32, (const u16*)ale1p, offsets, al_s1, al_d1, h1, b1, h1b);
    // layer 2 (h1 region reused as h2b/al2/rzv)
    k_gemm2<<<(NN + 63) / 64, TB, 0, stream>>>(h1b, W2, a2s, a2d, h2b, al_s2, al_d2);
    k_node2<<<NN / 4, TB, 0, stream>>>(src32, ale2p, offsets, al_s2, al_d2, h2b, b2, dout, rzv);
    k_alpha<<<NE / TB, TB, 0, stream>>>(ei, ale2, al_s2, al_d2, rzv, dout);
}

// Round 8
// 572.325 us; speedup vs baseline: 1.0996x; 1.0335x over previous
//
#include <hip/hip_runtime.h>

#define NN 100000
#define NE 1600000
#define NE2 1700000
#define OUT_EI 3200000
#define OUT_AL 6600000
#define SLOPE 0.2f
#define NB 391       // ceil(NN/256): dst buckets (256 nodes each)
#define EPB 6400     // edges per block in binning kernel
#define NBB 250      // NE / EPB
#define CAP 5120     // fixed bucket capacity (mean 4096, sigma 64 -> 16 sigma margin)
#define NNP 100096   // NN padded for aliased sub-buffers

typedef unsigned char u8;
typedef unsigned short u16;
typedef unsigned int u32;
typedef __bf16 bf16x8 __attribute__((ext_vector_type(8)));
typedef float f32x2 __attribute__((ext_vector_type(2)));
typedef float f32x4 __attribute__((ext_vector_type(4)));
typedef u32 u32x4 __attribute__((ext_vector_type(4)));

__device__ __forceinline__ float bf2f(u16 u){ return __uint_as_float(((u32)u) << 16); }
__device__ __forceinline__ u16 f2bf(float f){
    u32 x = __float_as_uint(f);
    x += 0x7FFFu + ((x >> 16) & 1u);   // round-to-nearest-even
    return (u16)(x >> 16);
}
__device__ __forceinline__ float eluf(float v){ return v > 0.f ? v : (__expf(v) - 1.f); }
__device__ __forceinline__ float lreluf(float v){ return fmaxf(v, SLOPE * v); }
__device__ __forceinline__ float sel4f(float a, float b, float c, float d, int s){
    float x = (s & 1) ? b : a;
    float y = (s & 1) ? d : c;
    return (s & 2) ? y : x;
}

// ================= edge logits precompute =================
__global__ __launch_bounds__(256) void k_ale(const float* __restrict__ eattr,
                                             const float* __restrict__ W1e, const float* __restrict__ a1e,
                                             const float* __restrict__ W2e, const float* __restrict__ a2e,
                                             u16* __restrict__ ale1, u16* __restrict__ ale2){
    __shared__ float sq1[64], sq2[16];
    int t = threadIdx.x;
    if (t < 64){
        int k = t >> 2, h = t & 3;
        float s = 0.f;
        #pragma unroll 8
        for (int c = 0; c < 32; c++) s += W1e[k * 128 + h * 32 + c] * a1e[h * 32 + c];
        sq1[t] = s;
    }
    if (t < 16){
        float s2 = 0.f;
        #pragma unroll 8
        for (int c = 0; c < 32; c++) s2 += W2e[t * 32 + c] * a2e[c];
        sq2[t] = s2;
    }
    __syncthreads();
    int gt = blockIdx.x * 256 + t;                   // NE*4 exact
    int e = gt >> 2, part = gt & 3;
    f32x4 av = ((const f32x4*)eattr)[(size_t)e * 4 + part];
    int j0 = part * 4;
    float p0 = 0, p1 = 0, p2 = 0, p3 = 0, p4 = 0;
    #pragma unroll
    for (int k = 0; k < 4; k++){
        float a = av[k]; int j = j0 + k;
        p0 += a * sq1[j * 4 + 0]; p1 += a * sq1[j * 4 + 1];
        p2 += a * sq1[j * 4 + 2]; p3 += a * sq1[j * 4 + 3];
        p4 += a * sq2[j];
    }
    #pragma unroll
    for (int m = 1; m < 4; m <<= 1){
        p0 += __shfl_xor(p0, m); p1 += __shfl_xor(p1, m);
        p2 += __shfl_xor(p2, m); p3 += __shfl_xor(p3, m); p4 += __shfl_xor(p4, m);
    }
    if (part == 0){
        ushort4 w; w.x = f2bf(p0); w.y = f2bf(p1); w.z = f2bf(p2); w.w = f2bf(p3);
        ((ushort4*)ale1)[e] = w;
        ale2[e] = f2bf(p4);
    }
}

// ================= bucketed CSR build (fixed-capacity buckets) =================
__global__ __launch_bounds__(256) void k_bscatter(const int* __restrict__ ei, const u16* __restrict__ ale1,
                                                  const u16* __restrict__ ale2,
                                                  int* __restrict__ bcnt, u32* __restrict__ binsP,
                                                  uint2* __restrict__ binsA, u16* __restrict__ binsA2){
    __shared__ int cnt[NB];
    __shared__ int base[NB];
    __shared__ int sdst[EPB];
    int t = threadIdx.x;
    for (int i = t; i < NB; i += 256) cnt[i] = 0;
    __syncthreads();
    int e0 = blockIdx.x * EPB;
    for (int i = t; i < EPB; i += 256){
        int dv = ei[NE + e0 + i];
        sdst[i] = dv;
        atomicAdd(&cnt[dv >> 8], 1);
    }
    __syncthreads();
    for (int i = t; i < NB; i += 256){
        int c = cnt[i];
        base[i] = c ? atomicAdd(&bcnt[i], c) : 0;    // bcnt ends as per-bucket totals
        cnt[i] = 0;
    }
    __syncthreads();
    const uint2* a1 = (const uint2*)ale1;
    for (int i = t; i < EPB; i += 256){
        int e = e0 + i;
        int dst = sdst[i];
        int b = dst >> 8;
        int r = base[b] + atomicAdd(&cnt[b], 1);
        if (r < CAP){                                // 16-sigma guard (never taken for this data)
            size_t pos = (size_t)b * CAP + r;
            binsP[pos] = ((u32)(dst & 255) << 24) | (u32)ei[e];
            binsA[pos] = a1[e];
            binsA2[pos] = ale2[e];
        }
    }
}

// per-bucket: cross-bucket prefix + degree hist + node scan -> offsets + fine scatter
__global__ __launch_bounds__(256) void k_fscatter(const u32* __restrict__ binsP, const uint2* __restrict__ binsA,
                                                  const u16* __restrict__ binsA2, const int* __restrict__ bcnt,
                                                  int* __restrict__ offsets,
                                                  int* __restrict__ src32, uint2* __restrict__ ale1p,
                                                  u16* __restrict__ ale2p){
    __shared__ int sc[512];
    __shared__ int d[256];
    __shared__ int s[256];
    __shared__ int cur[256];
    int t = threadIdx.x, b = blockIdx.x;
    int v0 = (t < NB) ? bcnt[t] : 0;
    int v1 = (t + 256 < NB) ? bcnt[t + 256] : 0;
    sc[t] = v0; sc[t + 256] = v1;
    d[t] = 0;
    __syncthreads();
    #pragma unroll
    for (int dd = 1; dd < 512; dd <<= 1){
        int x0 = (t >= dd) ? sc[t - dd] : 0;
        int x1 = (t + 256 >= dd) ? sc[t + 256 - dd] : 0;
        __syncthreads();
        sc[t] += x0; sc[t + 256] += x1;
        __syncthreads();
    }
    int myCnt = bcnt[b];
    int myBase = sc[b] - myCnt;                      // exclusive prefix of bucket b
    size_t bb = (size_t)b * CAP;
    for (int i = t; i < myCnt; i += 256)
        atomicAdd(&d[binsP[bb + i] >> 24], 1);
    __syncthreads();
    int dv = d[t];
    s[t] = dv; __syncthreads();
    #pragma unroll
    for (int dd = 1; dd < 256; dd <<= 1){
        int x = (t >= dd) ? s[t - dd] : 0;
        __syncthreads();
        s[t] += x;
        __syncthreads();
    }
    int n = b * 256 + t;
    int off = myBase + (s[t] - dv) + n;              // + n: one self-loop slot per preceding node
    if (n < NN) offsets[n] = off;
    cur[t] = off + 1;                                // real edges start after self-loop slot
    if (b == 0 && t == 0) offsets[NN] = NE + NN;
    __syncthreads();
    for (int i = t; i < myCnt; i += 256){
        u32 p = binsP[bb + i];
        int pos = atomicAdd(&cur[p >> 24], 1);
        src32[pos] = (int)(p & 0xFFFFFFu);
        ale1p[pos] = binsA[bb + i];
        ale2p[pos] = binsA2[bb + i];
    }
}

// ================= GEMM 1 (fp8 h1 output + fused al_s1/al_d1 epilogue) =================
__global__ __launch_bounds__(256) void k_gemm1(const float* __restrict__ x, const float* __restrict__ W,
                                               const float* __restrict__ a1s, const float* __restrict__ a1d,
                                               u8* __restrict__ h1,
                                               float* __restrict__ al_s, float* __restrict__ al_d){
    __shared__ __align__(16) u16 sW[128 * 136];      // transposed: sW[col*136+k]
    int t = threadIdx.x;
    for (int i = t; i < 128 * 128; i += 256){
        int k = i >> 7, c = i & 127;
        sW[c * 136 + k] = f2bf(W[i]);
    }
    __syncthreads();
    int lane = t & 63, wave = t >> 6;
    int quad = lane >> 4, m16 = lane & 15;
    int rowA = blockIdx.x * 64 + wave * 16 + m16;
    bf16x8 afr[4];
    if (rowA < NN){
        const f32x4* xr = (const f32x4*)(x + (size_t)rowA * 128);
        #pragma unroll
        for (int kk = 0; kk < 4; kk++){
            f32x4 va = xr[kk * 8 + quad * 2];
            f32x4 vb = xr[kk * 8 + quad * 2 + 1];
            #pragma unroll
            for (int i2 = 0; i2 < 4; i2++){ afr[kk][i2] = (__bf16)va[i2]; afr[kk][4 + i2] = (__bf16)vb[i2]; }
        }
    } else {
        #pragma unroll
        for (int kk = 0; kk < 4; kk++)
            #pragma unroll
            for (int i2 = 0; i2 < 8; i2++) afr[kk][i2] = (__bf16)0.f;
    }
    int rowbase = blockIdx.x * 64 + wave * 16 + quad * 4;
    float vsA[4][4], vdA[4][4];
    #pragma unroll
    for (int r = 0; r < 4; r++)
        #pragma unroll
        for (int h = 0; h < 4; h++){ vsA[r][h] = 0.f; vdA[r][h] = 0.f; }
    #pragma unroll
    for (int nt = 0; nt < 8; nt++){
        f32x4 acc = (f32x4){0.f, 0.f, 0.f, 0.f};
        const u16* wp = &sW[(nt * 16 + m16) * 136 + quad * 8];
        #pragma unroll
        for (int kk = 0; kk < 4; kk++){
            bf16x8 bfr = *(const bf16x8*)(wp + kk * 32);
            acc = __builtin_amdgcn_mfma_f32_16x16x32_bf16(afr[kk], bfr, acc, 0, 0, 0);
        }
        int col = nt * 16 + m16;
        float cs = a1s[col], cd = a1d[col];
        const int h = nt >> 1;                       // head uniform per nt
        #pragma unroll
        for (int r = 0; r < 4; r++){
            vsA[r][h] += acc[r] * cs;
            vdA[r][h] += acc[r] * cd;
            // fp8 pack: 4 consecutive cols -> one u32 store by lanes with m16%4==0
            float hi = __shfl_xor(acc[r], 1);
            u32 pk = (u32)__builtin_amdgcn_cvt_pk_fp8_f32(acc[r], hi, 0, false);
            u32 pk2 = (u32)__shfl_xor((int)pk, 2);
            if ((m16 & 3) == 0){
                int row = rowbase + r;
                if (row < NN){
                    u32 word = (pk & 0xFFFFu) | (pk2 << 16);
                    *(u32*)(h1 + (size_t)row * 128 + nt * 16 + m16) = word;
                }
            }
        }
    }
    #pragma unroll
    for (int r = 0; r < 4; r++)
        #pragma unroll
        for (int h = 0; h < 4; h++)
            #pragma unroll
            for (int m = 1; m < 16; m <<= 1){
                vsA[r][h] += __shfl_xor(vsA[r][h], m);
                vdA[r][h] += __shfl_xor(vdA[r][h], m);
            }
    int rs = m16 >> 2, hs = m16 & 3;                 // lane m16 writes (row rs, head hs)
    float s0 = sel4f(vsA[0][0], vsA[0][1], vsA[0][2], vsA[0][3], hs);
    float s1 = sel4f(vsA[1][0], vsA[1][1], vsA[1][2], vsA[1][3], hs);
    float s2 = sel4f(vsA[2][0], vsA[2][1], vsA[2][2], vsA[2][3], hs);
    float s3 = sel4f(vsA[3][0], vsA[3][1], vsA[3][2], vsA[3][3], hs);
    float d0 = sel4f(vdA[0][0], vdA[0][1], vdA[0][2], vdA[0][3], hs);
    float d1 = sel4f(vdA[1][0], vdA[1][1], vdA[1][2], vdA[1][3], hs);
    float d2 = sel4f(vdA[2][0], vdA[2][1], vdA[2][2], vdA[2][3], hs);
    float d3 = sel4f(vdA[3][0], vdA[3][1], vdA[3][2], vdA[3][3], hs);
    float souts = sel4f(s0, s1, s2, s3, rs);
    float soutd = sel4f(d0, d1, d2, d3, rs);
    int row = rowbase + rs;
    if (row < NN){
        al_s[row * 4 + hs] = souts;
        al_d[row * 4 + hs] = soutd;
    }
}

// ================= layer 1: FUSED softmax + aggregate (fp8 h1 gather, 3-deep pipeline) =================
__global__ __launch_bounds__(256) void k_node1(const int* __restrict__ src32, const u16* __restrict__ ale1u,
                                               const int* __restrict__ offsets,
                                               const float* __restrict__ al_s, const float* __restrict__ al_d,
                                               const u8* __restrict__ h1, const float* __restrict__ b1,
                                               u16* __restrict__ h1b){
    int wave = threadIdx.x >> 6, lane = threadIdx.x & 63;
    int n = blockIdx.x * 4 + wave;               // 25000*4 = NN exact
    int start = offsets[n], end = offsets[n + 1];
    int degr = end - start - 1;
    int g = lane >> 4, l = lane & 15, hq = l >> 2;   // channels 8l..8l+7, head = l>>2
    float aldh = al_d[n * 4 + hq];
    const uint2* h1v = (const uint2*)h1;             // 16 uint2 (8 fp8) per row
    float acc[8];
    #pragma unroll
    for (int k = 0; k < 8; k++) acc[k] = 0.f;
    float z = 0.f, sa = 0.f;
    // 3-deep pipeline: src 2 ahead, payload 1 ahead
    int i = start + 1 + g;
    int i1 = i + 4, i2 = i + 8;
    int src0 = (i  < end) ? __builtin_nontemporal_load(src32 + i)  : n;
    int src1 = (i1 < end) ? __builtin_nontemporal_load(src32 + i1) : n;
    float a0   = (i < end) ? bf2f(__builtin_nontemporal_load(ale1u + (size_t)i * 4 + hq)) : 0.f;
    float als0 = al_s[src0 * 4 + hq];
    uint2 v0 = h1v[(size_t)src0 * 16 + l];
    while (i < end){
        int src2 = (i2 < end) ? __builtin_nontemporal_load(src32 + i2) : n;
        float a1v  = (i1 < end) ? bf2f(__builtin_nontemporal_load(ale1u + (size_t)i1 * 4 + hq)) : 0.f;
        float als1 = al_s[src1 * 4 + hq];
        uint2 v1 = h1v[(size_t)src1 * 16 + l];
        float e = __expf(lreluf(als0 + aldh + a0));
        z += e; sa += a0;
        f32x2 d0 = __builtin_amdgcn_cvt_pk_f32_fp8(v0.x, false);
        f32x2 d1 = __builtin_amdgcn_cvt_pk_f32_fp8(v0.x, true);
        f32x2 d2 = __builtin_amdgcn_cvt_pk_f32_fp8(v0.y, false);
        f32x2 d3 = __builtin_amdgcn_cvt_pk_f32_fp8(v0.y, true);
        acc[0] += e * d0[0]; acc[1] += e * d0[1];
        acc[2] += e * d1[0]; acc[3] += e * d1[1];
        acc[4] += e * d2[0]; acc[5] += e * d2[1];
        acc[6] += e * d3[0]; acc[7] += e * d3[1];
        i = i1; i1 = i2; i2 += 4;
        src1 = src2; a0 = a1v; als0 = als1; v0 = v1;
    }
    // reduce z/sa across the 4 groups
    z += __shfl_xor(z, 16); z += __shfl_xor(z, 32);
    sa += __shfl_xor(sa, 16); sa += __shfl_xor(sa, 32);
    float inv_deg = 1.f / fmaxf((float)degr, 1.f);
    float ps = __expf(lreluf(al_s[n * 4 + hq] + aldh + sa * inv_deg));
    z += ps;
    if (g == 0){                                     // self contribution, counted once
        uint2 v = h1v[(size_t)n * 16 + l];
        f32x2 d0 = __builtin_amdgcn_cvt_pk_f32_fp8(v.x, false);
        f32x2 d1 = __builtin_amdgcn_cvt_pk_f32_fp8(v.x, true);
        f32x2 d2 = __builtin_amdgcn_cvt_pk_f32_fp8(v.y, false);
        f32x2 d3 = __builtin_amdgcn_cvt_pk_f32_fp8(v.y, true);
        acc[0] += ps * d0[0]; acc[1] += ps * d0[1];
        acc[2] += ps * d1[0]; acc[3] += ps * d1[1];
        acc[4] += ps * d2[0]; acc[5] += ps * d2[1];
        acc[6] += ps * d3[0]; acc[7] += ps * d3[1];
    }
    #pragma unroll
    for (int k = 0; k < 8; k++){
        acc[k] += __shfl_xor(acc[k], 16);
        acc[k] += __shfl_xor(acc[k], 32);
    }
    if (g == 0){
        float rz = 1.f / z;
        u32x4 w;
        #pragma unroll
        for (int k = 0; k < 4; k++){
            float v0e = eluf(acc[2 * k]     * rz + b1[l * 8 + 2 * k]);
            float v1e = eluf(acc[2 * k + 1] * rz + b1[l * 8 + 2 * k + 1]);
            w[k] = (u32)f2bf(v0e) | ((u32)f2bf(v1e) << 16);
        }
        ((u32x4*)h1b)[(size_t)n * 16 + l] = w;
    }
}

// ================= GEMM 2 (fp8 h2b output + fused al_s2/al_d2 epilogue) =================
__global__ __launch_bounds__(256) void k_gemm2(const u16* __restrict__ hin, const float* __restrict__ W,
                                               const float* __restrict__ a2s, const float* __restrict__ a2d,
                                               u8* __restrict__ h2b,
                                               float* __restrict__ al_s, float* __restrict__ al_d){
    __shared__ __align__(16) u16 sW[32 * 136];
    int t = threadIdx.x;
    for (int i = t; i < 128 * 32; i += 256){
        int k = i >> 5, c = i & 31;
        sW[c * 136 + k] = f2bf(W[i]);
    }
    __syncthreads();
    int lane = t & 63, wave = t >> 6;
    int quad = lane >> 4, m16 = lane & 15;
    int rowA = blockIdx.x * 64 + wave * 16 + m16;
    bf16x8 afr[4];
    if (rowA < NN){
        const u16* xr = hin + (size_t)rowA * 128 + quad * 8;
        #pragma unroll
        for (int kk = 0; kk < 4; kk++) afr[kk] = *(const bf16x8*)(xr + kk * 32);
    } else {
        #pragma unroll
        for (int kk = 0; kk < 4; kk++)
            #pragma unroll
            for (int i2 = 0; i2 < 8; i2++) afr[kk][i2] = (__bf16)0.f;
    }
    int rowbase = blockIdx.x * 64 + wave * 16 + quad * 4;
    float vs2[4], vd2[4];
    #pragma unroll
    for (int r = 0; r < 4; r++){ vs2[r] = 0.f; vd2[r] = 0.f; }
    #pragma unroll
    for (int nt = 0; nt < 2; nt++){
        f32x4 acc = (f32x4){0.f, 0.f, 0.f, 0.f};
        const u16* wp = &sW[(nt * 16 + m16) * 136 + quad * 8];
        #pragma unroll
        for (int kk = 0; kk < 4; kk++){
            bf16x8 bfr = *(const bf16x8*)(wp + kk * 32);
            acc = __builtin_amdgcn_mfma_f32_16x16x32_bf16(afr[kk], bfr, acc, 0, 0, 0);
        }
        int col = nt * 16 + m16;
        float cs = a2s[col], cd = a2d[col];
        #pragma unroll
        for (int r = 0; r < 4; r++){
            vs2[r] += acc[r] * cs;
            vd2[r] += acc[r] * cd;
            float hi = __shfl_xor(acc[r], 1);
            u32 pk = (u32)__builtin_amdgcn_cvt_pk_fp8_f32(acc[r], hi, 0, false);
            u32 pk2 = (u32)__shfl_xor((int)pk, 2);
            if ((m16 & 3) == 0){
                int row = rowbase + r;
                if (row < NN){
                    u32 word = (pk & 0xFFFFu) | (pk2 << 16);
                    *(u32*)(h2b + (size_t)row * 32 + nt * 16 + m16) = word;
                }
            }
        }
    }
    #pragma unroll
    for (int r = 0; r < 4; r++)
        #pragma unroll
        for (int m = 1; m < 16; m <<= 1){
            vs2[r] += __shfl_xor(vs2[r], m);
            vd2[r] += __shfl_xor(vd2[r], m);
        }
    if (m16 < 4){
        int row = rowbase + m16;
        if (row < NN){
            al_s[row] = sel4f(vs2[0], vs2[1], vs2[2], vs2[3], m16);
            al_d[row] = sel4f(vd2[0], vd2[1], vd2[2], vd2[3], m16);
        }
    }
}

// ================= layer 2: FUSED softmax + aggregate (fp8 h2b gather, 3-deep pipeline) =================
__global__ __launch_bounds__(256) void k_node2(const int* __restrict__ src32, const u16* __restrict__ ale2p,
                                               const int* __restrict__ offsets,
                                               const float* __restrict__ al_s, const float* __restrict__ al_d,
                                               const u8* __restrict__ h2b, const float* __restrict__ b2,
                                               float* __restrict__ dout, float* __restrict__ rzv){
    int wave = threadIdx.x >> 6, lane = threadIdx.x & 63;
    int n = blockIdx.x * 4 + wave;
    int start = offsets[n], end = offsets[n + 1];
    int degr = end - start - 1;
    float aldn = al_d[n];
    int g = lane >> 3, l = lane & 7;                 // 8 edges in flight, channels l*4..l*4+3
    const u32* h2v = (const u32*)h2b;                // 8 u32 (4 fp8) per row
    f32x4 acc = (f32x4){0.f, 0.f, 0.f, 0.f};
    float z = 0.f, sa = 0.f;
    int i = start + 1 + g;
    int i1 = i + 8, i2 = i + 16;
    int src0 = (i  < end) ? __builtin_nontemporal_load(src32 + i)  : n;
    int src1 = (i1 < end) ? __builtin_nontemporal_load(src32 + i1) : n;
    float a0   = (i < end) ? bf2f(__builtin_nontemporal_load(ale2p + i)) : 0.f;
    float als0 = al_s[src0];
    u32 v0 = h2v[(size_t)src0 * 8 + l];
    while (i < end){
        int src2 = (i2 < end) ? __builtin_nontemporal_load(src32 + i2) : n;
        float a1v  = (i1 < end) ? bf2f(__builtin_nontemporal_load(ale2p + i1)) : 0.f;
        float als1 = al_s[src1];
        u32 v1 = h2v[(size_t)src1 * 8 + l];
        float e = __expf(lreluf(als0 + aldn + a0));
        z += e; sa += a0;
        f32x2 d0 = __builtin_amdgcn_cvt_pk_f32_fp8(v0, false);
        f32x2 d1 = __builtin_amdgcn_cvt_pk_f32_fp8(v0, true);
        acc[0] += e * d0[0]; acc[1] += e * d0[1];
        acc[2] += e * d1[0]; acc[3] += e * d1[1];
        i = i1; i1 = i2; i2 += 8;
        src1 = src2; a0 = a1v; als0 = als1; v0 = v1;
    }
    z += __shfl_xor(z, 8); z += __shfl_xor(z, 16); z += __shfl_xor(z, 32);
    sa += __shfl_xor(sa, 8); sa += __shfl_xor(sa, 16); sa += __shfl_xor(sa, 32);
    float mal = sa / fmaxf((float)degr, 1.f);
    float ps = __expf(lreluf(al_s[n] + aldn + mal));
    z += ps;
    float rz = 1.f / z;
    if (g == 0){                                     // self contribution
        u32 v = h2v[(size_t)n * 8 + l];
        f32x2 d0 = __builtin_amdgcn_cvt_pk_f32_fp8(v, false);
        f32x2 d1 = __builtin_amdgcn_cvt_pk_f32_fp8(v, true);
        acc[0] += ps * d0[0]; acc[1] += ps * d0[1];
        acc[2] += ps * d1[0]; acc[3] += ps * d1[1];
    }
    if (lane == 0){
        rzv[n] = rz;
        dout[OUT_AL + NE + n] = ps * rz;             // self-loop alpha
        dout[OUT_EI + NE + n] = (float)n;            // self-loop edge_index entries
        dout[OUT_EI + NE2 + NE + n] = (float)n;
    }
    #pragma unroll
    for (int k = 0; k < 4; k++){
        acc[k] += __shfl_xor(acc[k], 8);
        acc[k] += __shfl_xor(acc[k], 16);
        acc[k] += __shfl_xor(acc[k], 32);
    }
    if (g == 0){
        f32x4 w;
        #pragma unroll
        for (int k = 0; k < 4; k++) w[k] = eluf(acc[k] * rz + b2[l * 4 + k]);
        ((f32x4*)dout)[(size_t)n * 8 + l] = w;
    }
}

// alpha + edge_index for real edges, original edge order: all writes sequential
__global__ __launch_bounds__(256) void k_alpha(const int* __restrict__ ei, const u16* __restrict__ ale2,
                                               const float* __restrict__ al_s, const float* __restrict__ al_d,
                                               const float* __restrict__ rzv, float* __restrict__ dout){
    int e = blockIdx.x * 256 + threadIdx.x;          // NE exact
    int src = ei[e], dst = ei[NE + e];
    float a = bf2f(ale2[e]);
    float ev = __expf(lreluf(al_s[src] + al_d[dst] + a));
    __builtin_nontemporal_store(ev * rzv[dst], &dout[OUT_AL + e]);
    __builtin_nontemporal_store((float)src, &dout[OUT_EI + e]);
    __builtin_nontemporal_store((float)dst, &dout[OUT_EI + NE2 + e]);
}

extern "C" void kernel_launch(void* const* d_in, const int* in_sizes, int n_in,
                              void* d_out, int out_size, void* d_ws, size_t ws_size,
                              hipStream_t stream) {
    const float* x     = (const float*)d_in[0];
    const int*   ei    = (const int*)d_in[1];
    const float* eattr = (const float*)d_in[2];
    const float* W1    = (const float*)d_in[3];
    const float* W1e   = (const float*)d_in[4];
    const float* a1s   = (const float*)d_in[5];
    const float* a1d   = (const float*)d_in[6];
    const float* a1e   = (const float*)d_in[7];
    const float* b1    = (const float*)d_in[8];
    const float* W2    = (const float*)d_in[9];
    const float* W2e   = (const float*)d_in[10];
    const float* a2s   = (const float*)d_in[11];
    const float* a2d   = (const float*)d_in[12];
    const float* a2e   = (const float*)d_in[13];
    const float* b2    = (const float*)d_in[14];
    float* dout = (float*)d_out;

    char* ws = (char*)d_ws;
    size_t off = 0;
    auto alloc = [&](size_t bytes) -> void* {
        void* p = ws + off;
        off += (bytes + 255) & ~(size_t)255;
        return p;
    };
    // --- zero-initialized: bucket counters only ---
    int* bcnt = (int*)alloc((size_t)NB * 4);
    size_t zero_bytes = off;
    // --- rest fully written before read ---
    int*     offsets = (int*)alloc((size_t)(NN + 1) * 4);
    u32*     binsP   = (u32*)alloc((size_t)NB * CAP * 4);    // dead after k_fscatter
    uint2*   binsA   = (uint2*)alloc((size_t)NB * CAP * 8);  // dead after k_fscatter
    u16*     binsA2  = (u16*)alloc((size_t)NB * CAP * 2);    // dead after k_fscatter
    int*     src32   = (int*)alloc((size_t)NE2 * 4);
    uint2*   ale1p   = (uint2*)alloc((size_t)NE2 * 8);
    u16*     ale2p   = (u16*)alloc((size_t)NE2 * 2);
    u16*     ale1    = (u16*)alloc((size_t)NE * 4 * 2);      // dead after k_bscatter
    u16*     ale2    = (u16*)alloc((size_t)NE * 2);          // live until k_alpha
    float*   al_s1   = (float*)alloc((size_t)NN * 4 * 4);
    float*   al_d1   = (float*)alloc((size_t)NN * 4 * 4);
    u8*      h1      = (u8*)alloc((size_t)NN * 128);         // fp8; dead after k_node1
    // aliases into dead regions:
    u16*   h1b   = (u16*)binsP;                              // 25.6 MB in 28 MB bins region (dead after fscatter)
    char*  h1r   = (char*)h1;                                // h1 region (12.8 MB) reused after k_node1:
    u8*    h2b   = (u8*)h1r;                                 //   NN*32 = 3.2 MB (fp8)
    float* al_s2 = (float*)(h1r + 3200000);                  //   NN*4
    float* al_d2 = al_s2 + NNP;
    float* rzv   = al_d2 + NNP;

    const int TB = 256;
    hipMemsetAsync(d_ws, 0, zero_bytes, stream);

    // edge logits
    k_ale<<<NE * 4 / TB, TB, 0, stream>>>(eattr, W1e, a1e, W2e, a2e, ale1, ale2);
    // bucketed CSR build
    k_bscatter<<<NBB, TB, 0, stream>>>(ei, ale1, ale2, bcnt, binsP, binsA, binsA2);
    k_fscatter<<<NB, TB, 0, stream>>>(binsP, binsA, binsA2, bcnt, offsets, src32, ale1p, ale2p);
    // layer 1
    k_gemm1<<<(NN + 63) / 64, TB, 0, stream>>>(x, W1, a1s, a1d, h1, al_s1, al_d1);
    k_node1<<<NN / 4, TB, 0, stream>>>(src32, (const u16*)ale1p, offsets, al_s1, al_d1, h1, b1, h1b);
    // layer 2 (h1 region reused as h2b/al2/rzv)
    k_gemm2<<<(NN + 63) / 64, TB, 0, stream>>>(h1b, W2, a2s, a2d, h2b, al_s2, al_d2);
    k_node2<<<NN / 4, TB, 0, stream>>>(src32, ale2p, offsets, al_s2, al_d2, h2b, b2, dout, rzv);
    k_alpha<<<NE / TB, TB, 0, stream>>>(ei, ale2, al_s2, al_d2, rzv, dout);
}

// Round 9
// 535.076 us; speedup vs baseline: 1.1762x; 1.0696x over previous
//
#include <hip/hip_runtime.h>

#define NN 100000
#define NE 1600000
#define NE2 1700000
#define OUT_EI 3200000
#define OUT_AL 6600000
#define SLOPE 0.2f
#define NB 391       // ceil(NN/256): dst buckets (256 nodes each)
#define EPB 6400     // edges per block in binning kernel
#define NBB 250      // NE / EPB
#define CAP 5120     // fixed bucket capacity (mean 4096, sigma 64 -> 16 sigma margin)
#define NNP 100096   // NN padded for aliased sub-buffers

typedef unsigned char u8;
typedef unsigned short u16;
typedef unsigned int u32;
typedef __bf16 bf16x8 __attribute__((ext_vector_type(8)));
typedef float f32x2 __attribute__((ext_vector_type(2)));
typedef float f32x4 __attribute__((ext_vector_type(4)));
typedef u32 u32x4 __attribute__((ext_vector_type(4)));

__device__ __forceinline__ float bf2f(u16 u){ return __uint_as_float(((u32)u) << 16); }
__device__ __forceinline__ u16 f2bf(float f){
    u32 x = __float_as_uint(f);
    x += 0x7FFFu + ((x >> 16) & 1u);   // round-to-nearest-even
    return (u16)(x >> 16);
}
__device__ __forceinline__ float eluf(float v){ return v > 0.f ? v : (__expf(v) - 1.f); }
__device__ __forceinline__ float lreluf(float v){ return fmaxf(v, SLOPE * v); }
__device__ __forceinline__ float sel4f(float a, float b, float c, float d, int s){
    float x = (s & 1) ? b : a;
    float y = (s & 1) ? d : c;
    return (s & 2) ? y : x;
}

// ================= bucketed CSR build + FUSED edge-logit computation =================
// Reads eattr sequentially, computes ale1 (4 heads) + ale2 per edge in-register via
// wave-uniform LDS q-vectors, and scatters payload into fixed-capacity buckets.
// Also writes ale2 in original edge order (for k_alpha). k_ale deleted.
__global__ __launch_bounds__(256) void k_bscatter(const int* __restrict__ ei, const float* __restrict__ eattr,
                                                  const float* __restrict__ W1e, const float* __restrict__ a1e,
                                                  const float* __restrict__ W2e, const float* __restrict__ a2e,
                                                  int* __restrict__ bcnt, u32* __restrict__ binsP,
                                                  uint2* __restrict__ binsA, u16* __restrict__ binsA2,
                                                  u16* __restrict__ ale2seq){
    __shared__ float sq1[64], sq2[16];
    __shared__ int cnt[NB];
    __shared__ int base[NB];
    __shared__ int sdst[EPB];
    int t = threadIdx.x;
    if (t < 64){
        int k = t >> 2, h = t & 3;
        float s = 0.f;
        #pragma unroll 8
        for (int c = 0; c < 32; c++) s += W1e[k * 128 + h * 32 + c] * a1e[h * 32 + c];
        sq1[t] = s;
    }
    if (t < 16){
        float s2 = 0.f;
        #pragma unroll 8
        for (int c = 0; c < 32; c++) s2 += W2e[t * 32 + c] * a2e[c];
        sq2[t] = s2;
    }
    for (int i = t; i < NB; i += 256) cnt[i] = 0;
    __syncthreads();
    int e0 = blockIdx.x * EPB;
    for (int i = t; i < EPB; i += 256){
        int dv = ei[NE + e0 + i];
        sdst[i] = dv;
        atomicAdd(&cnt[dv >> 8], 1);
    }
    __syncthreads();
    for (int i = t; i < NB; i += 256){
        int c = cnt[i];
        base[i] = c ? atomicAdd(&bcnt[i], c) : 0;    // bcnt ends as per-bucket totals
        cnt[i] = 0;
    }
    __syncthreads();
    for (int i = t; i < EPB; i += 256){
        int e = e0 + i;
        const f32x4* ap = (const f32x4*)(eattr + (size_t)e * 16);
        float p0 = 0, p1 = 0, p2 = 0, p3 = 0, p4 = 0;
        #pragma unroll
        for (int j = 0; j < 4; j++){
            f32x4 av = ap[j];
            #pragma unroll
            for (int k = 0; k < 4; k++){
                float a = av[k]; int jj = j * 4 + k;
                p0 += a * sq1[jj * 4 + 0]; p1 += a * sq1[jj * 4 + 1];
                p2 += a * sq1[jj * 4 + 2]; p3 += a * sq1[jj * 4 + 3];
                p4 += a * sq2[jj];
            }
        }
        u32 w01 = (u32)f2bf(p0) | ((u32)f2bf(p1) << 16);
        u32 w23 = (u32)f2bf(p2) | ((u32)f2bf(p3) << 16);
        u16 w4 = f2bf(p4);
        ale2seq[e] = w4;
        int dst = sdst[i];
        int b = dst >> 8;
        int r = base[b] + atomicAdd(&cnt[b], 1);
        if (r < CAP){                                // 16-sigma guard (never taken for this data)
            size_t pos = (size_t)b * CAP + r;
            binsP[pos] = ((u32)(dst & 255) << 24) | (u32)ei[e];
            uint2 wa; wa.x = w01; wa.y = w23;
            binsA[pos] = wa;
            binsA2[pos] = w4;
        }
    }
}

// per-bucket: cross-bucket prefix + degree hist + node scan -> offsets + fine scatter
__global__ __launch_bounds__(256) void k_fscatter(const u32* __restrict__ binsP, const uint2* __restrict__ binsA,
                                                  const u16* __restrict__ binsA2, const int* __restrict__ bcnt,
                                                  int* __restrict__ offsets,
                                                  int* __restrict__ src32, uint2* __restrict__ ale1p,
                                                  u16* __restrict__ ale2p){
    __shared__ int sc[512];
    __shared__ int d[256];
    __shared__ int s[256];
    __shared__ int cur[256];
    int t = threadIdx.x, b = blockIdx.x;
    int v0 = (t < NB) ? bcnt[t] : 0;
    int v1 = (t + 256 < NB) ? bcnt[t + 256] : 0;
    sc[t] = v0; sc[t + 256] = v1;
    d[t] = 0;
    __syncthreads();
    #pragma unroll
    for (int dd = 1; dd < 512; dd <<= 1){
        int x0 = (t >= dd) ? sc[t - dd] : 0;
        int x1 = (t + 256 >= dd) ? sc[t + 256 - dd] : 0;
        __syncthreads();
        sc[t] += x0; sc[t + 256] += x1;
        __syncthreads();
    }
    int myCnt = bcnt[b];
    int myBase = sc[b] - myCnt;                      // exclusive prefix of bucket b
    size_t bb = (size_t)b * CAP;
    for (int i = t; i < myCnt; i += 256)
        atomicAdd(&d[binsP[bb + i] >> 24], 1);
    __syncthreads();
    int dv = d[t];
    s[t] = dv; __syncthreads();
    #pragma unroll
    for (int dd = 1; dd < 256; dd <<= 1){
        int x = (t >= dd) ? s[t - dd] : 0;
        __syncthreads();
        s[t] += x;
        __syncthreads();
    }
    int n = b * 256 + t;
    int off = myBase + (s[t] - dv) + n;              // + n: one self-loop slot per preceding node
    if (n < NN) offsets[n] = off;
    cur[t] = off + 1;                                // real edges start after self-loop slot
    if (b == 0 && t == 0) offsets[NN] = NE + NN;
    __syncthreads();
    for (int i = t; i < myCnt; i += 256){
        u32 p = binsP[bb + i];
        int pos = atomicAdd(&cur[p >> 24], 1);
        src32[pos] = (int)(p & 0xFFFFFFu);
        ale1p[pos] = binsA[bb + i];
        ale2p[pos] = binsA2[bb + i];
    }
}

// ================= GEMM 1 (fp8 h1 output + fused al_s1/al_d1 epilogue) =================
__global__ __launch_bounds__(256) void k_gemm1(const float* __restrict__ x, const float* __restrict__ W,
                                               const float* __restrict__ a1s, const float* __restrict__ a1d,
                                               u8* __restrict__ h1,
                                               float* __restrict__ al_s, float* __restrict__ al_d){
    __shared__ __align__(16) u16 sW[128 * 136];      // transposed: sW[col*136+k]
    int t = threadIdx.x;
    for (int i = t; i < 128 * 128; i += 256){
        int k = i >> 7, c = i & 127;
        sW[c * 136 + k] = f2bf(W[i]);
    }
    __syncthreads();
    int lane = t & 63, wave = t >> 6;
    int quad = lane >> 4, m16 = lane & 15;
    int rowA = blockIdx.x * 64 + wave * 16 + m16;
    bf16x8 afr[4];
    if (rowA < NN){
        const f32x4* xr = (const f32x4*)(x + (size_t)rowA * 128);
        #pragma unroll
        for (int kk = 0; kk < 4; kk++){
            f32x4 va = xr[kk * 8 + quad * 2];
            f32x4 vb = xr[kk * 8 + quad * 2 + 1];
            #pragma unroll
            for (int i2 = 0; i2 < 4; i2++){ afr[kk][i2] = (__bf16)va[i2]; afr[kk][4 + i2] = (__bf16)vb[i2]; }
        }
    } else {
        #pragma unroll
        for (int kk = 0; kk < 4; kk++)
            #pragma unroll
            for (int i2 = 0; i2 < 8; i2++) afr[kk][i2] = (__bf16)0.f;
    }
    int rowbase = blockIdx.x * 64 + wave * 16 + quad * 4;
    float vsA[4][4], vdA[4][4];
    #pragma unroll
    for (int r = 0; r < 4; r++)
        #pragma unroll
        for (int h = 0; h < 4; h++){ vsA[r][h] = 0.f; vdA[r][h] = 0.f; }
    #pragma unroll
    for (int nt = 0; nt < 8; nt++){
        f32x4 acc = (f32x4){0.f, 0.f, 0.f, 0.f};
        const u16* wp = &sW[(nt * 16 + m16) * 136 + quad * 8];
        #pragma unroll
        for (int kk = 0; kk < 4; kk++){
            bf16x8 bfr = *(const bf16x8*)(wp + kk * 32);
            acc = __builtin_amdgcn_mfma_f32_16x16x32_bf16(afr[kk], bfr, acc, 0, 0, 0);
        }
        int col = nt * 16 + m16;
        float cs = a1s[col], cd = a1d[col];
        const int h = nt >> 1;                       // head uniform per nt
        #pragma unroll
        for (int r = 0; r < 4; r++){
            vsA[r][h] += acc[r] * cs;
            vdA[r][h] += acc[r] * cd;
            // fp8 pack: 4 consecutive cols -> one u32 store by lanes with m16%4==0
            float hi = __shfl_xor(acc[r], 1);
            u32 pk = (u32)__builtin_amdgcn_cvt_pk_fp8_f32(acc[r], hi, 0, false);
            u32 pk2 = (u32)__shfl_xor((int)pk, 2);
            if ((m16 & 3) == 0){
                int row = rowbase + r;
                if (row < NN){
                    u32 word = (pk & 0xFFFFu) | (pk2 << 16);
                    *(u32*)(h1 + (size_t)row * 128 + nt * 16 + m16) = word;
                }
            }
        }
    }
    #pragma unroll
    for (int r = 0; r < 4; r++)
        #pragma unroll
        for (int h = 0; h < 4; h++)
            #pragma unroll
            for (int m = 1; m < 16; m <<= 1){
                vsA[r][h] += __shfl_xor(vsA[r][h], m);
                vdA[r][h] += __shfl_xor(vdA[r][h], m);
            }
    int rs = m16 >> 2, hs = m16 & 3;                 // lane m16 writes (row rs, head hs)
    float s0 = sel4f(vsA[0][0], vsA[0][1], vsA[0][2], vsA[0][3], hs);
    float s1 = sel4f(vsA[1][0], vsA[1][1], vsA[1][2], vsA[1][3], hs);
    float s2 = sel4f(vsA[2][0], vsA[2][1], vsA[2][2], vsA[2][3], hs);
    float s3 = sel4f(vsA[3][0], vsA[3][1], vsA[3][2], vsA[3][3], hs);
    float d0 = sel4f(vdA[0][0], vdA[0][1], vdA[0][2], vdA[0][3], hs);
    float d1 = sel4f(vdA[1][0], vdA[1][1], vdA[1][2], vdA[1][3], hs);
    float d2 = sel4f(vdA[2][0], vdA[2][1], vdA[2][2], vdA[2][3], hs);
    float d3 = sel4f(vdA[3][0], vdA[3][1], vdA[3][2], vdA[3][3], hs);
    float souts = sel4f(s0, s1, s2, s3, rs);
    float soutd = sel4f(d0, d1, d2, d3, rs);
    int row = rowbase + rs;
    if (row < NN){
        al_s[row * 4 + hs] = souts;
        al_d[row * 4 + hs] = soutd;
    }
}

// ================= layer 1: FUSED softmax + aggregate =================
// 8-lane groups -> 8 edges in flight (double the MLP of r8), 3-deep pipeline,
// fp8 h1 gather (uint4 = 16 channels/lane), fp8 h1b output.
__global__ __launch_bounds__(256) void k_node1(const int* __restrict__ src32, const u16* __restrict__ ale1u,
                                               const int* __restrict__ offsets,
                                               const float* __restrict__ al_s, const float* __restrict__ al_d,
                                               const u8* __restrict__ h1, const float* __restrict__ b1,
                                               u8* __restrict__ h1b){
    int wave = threadIdx.x >> 6, lane = threadIdx.x & 63;
    int n = blockIdx.x * 4 + wave;               // 25000*4 = NN exact
    int start = offsets[n], end = offsets[n + 1];
    int degr = end - start - 1;
    int g = lane >> 3, l = lane & 7, hq = l >> 1;    // channels 16l..16l+15, head = l>>1
    float aldh = al_d[n * 4 + hq];
    const uint4* h1v = (const uint4*)h1;             // 8 uint4 (16 fp8) per row
    float acc[16];
    #pragma unroll
    for (int k = 0; k < 16; k++) acc[k] = 0.f;
    float z = 0.f, sa = 0.f;
    // 3-deep pipeline: src 2 ahead, payload 1 ahead
    int i = start + 1 + g;
    int i1 = i + 8, i2 = i + 16;
    int src0 = (i  < end) ? __builtin_nontemporal_load(src32 + i)  : n;
    int src1 = (i1 < end) ? __builtin_nontemporal_load(src32 + i1) : n;
    float a0   = (i < end) ? bf2f(__builtin_nontemporal_load(ale1u + (size_t)i * 4 + hq)) : 0.f;
    float als0 = al_s[src0 * 4 + hq];
    uint4 v0 = h1v[(size_t)src0 * 8 + l];
    while (i < end){
        int src2 = (i2 < end) ? __builtin_nontemporal_load(src32 + i2) : n;
        float a1v  = (i1 < end) ? bf2f(__builtin_nontemporal_load(ale1u + (size_t)i1 * 4 + hq)) : 0.f;
        float als1 = al_s[src1 * 4 + hq];
        uint4 v1 = h1v[(size_t)src1 * 8 + l];
        float e = __expf(lreluf(als0 + aldh + a0));
        z += e; sa += a0;
        f32x2 d0 = __builtin_amdgcn_cvt_pk_f32_fp8(v0.x, false);
        f32x2 d1 = __builtin_amdgcn_cvt_pk_f32_fp8(v0.x, true);
        f32x2 d2 = __builtin_amdgcn_cvt_pk_f32_fp8(v0.y, false);
        f32x2 d3 = __builtin_amdgcn_cvt_pk_f32_fp8(v0.y, true);
        f32x2 d4 = __builtin_amdgcn_cvt_pk_f32_fp8(v0.z, false);
        f32x2 d5 = __builtin_amdgcn_cvt_pk_f32_fp8(v0.z, true);
        f32x2 d6 = __builtin_amdgcn_cvt_pk_f32_fp8(v0.w, false);
        f32x2 d7 = __builtin_amdgcn_cvt_pk_f32_fp8(v0.w, true);
        acc[0]  += e * d0[0]; acc[1]  += e * d0[1];
        acc[2]  += e * d1[0]; acc[3]  += e * d1[1];
        acc[4]  += e * d2[0]; acc[5]  += e * d2[1];
        acc[6]  += e * d3[0]; acc[7]  += e * d3[1];
        acc[8]  += e * d4[0]; acc[9]  += e * d4[1];
        acc[10] += e * d5[0]; acc[11] += e * d5[1];
        acc[12] += e * d6[0]; acc[13] += e * d6[1];
        acc[14] += e * d7[0]; acc[15] += e * d7[1];
        i = i1; i1 = i2; i2 += 8;
        src1 = src2; a0 = a1v; als0 = als1; v0 = v1;
    }
    // reduce z/sa across the 8 groups
    z += __shfl_xor(z, 8); z += __shfl_xor(z, 16); z += __shfl_xor(z, 32);
    sa += __shfl_xor(sa, 8); sa += __shfl_xor(sa, 16); sa += __shfl_xor(sa, 32);
    float inv_deg = 1.f / fmaxf((float)degr, 1.f);
    float ps = __expf(lreluf(al_s[n * 4 + hq] + aldh + sa * inv_deg));
    z += ps;
    if (g == 0){                                     // self contribution, counted once
        uint4 v = h1v[(size_t)n * 8 + l];
        f32x2 d0 = __builtin_amdgcn_cvt_pk_f32_fp8(v.x, false);
        f32x2 d1 = __builtin_amdgcn_cvt_pk_f32_fp8(v.x, true);
        f32x2 d2 = __builtin_amdgcn_cvt_pk_f32_fp8(v.y, false);
        f32x2 d3 = __builtin_amdgcn_cvt_pk_f32_fp8(v.y, true);
        f32x2 d4 = __builtin_amdgcn_cvt_pk_f32_fp8(v.z, false);
        f32x2 d5 = __builtin_amdgcn_cvt_pk_f32_fp8(v.z, true);
        f32x2 d6 = __builtin_amdgcn_cvt_pk_f32_fp8(v.w, false);
        f32x2 d7 = __builtin_amdgcn_cvt_pk_f32_fp8(v.w, true);
        acc[0]  += ps * d0[0]; acc[1]  += ps * d0[1];
        acc[2]  += ps * d1[0]; acc[3]  += ps * d1[1];
        acc[4]  += ps * d2[0]; acc[5]  += ps * d2[1];
        acc[6]  += ps * d3[0]; acc[7]  += ps * d3[1];
        acc[8]  += ps * d4[0]; acc[9]  += ps * d4[1];
        acc[10] += ps * d5[0]; acc[11] += ps * d5[1];
        acc[12] += ps * d6[0]; acc[13] += ps * d6[1];
        acc[14] += ps * d7[0]; acc[15] += ps * d7[1];
    }
    #pragma unroll
    for (int k = 0; k < 16; k++){
        acc[k] += __shfl_xor(acc[k], 8);
        acc[k] += __shfl_xor(acc[k], 16);
        acc[k] += __shfl_xor(acc[k], 32);
    }
    if (g == 0){                                     // lanes 0..7 write 16 fp8 channels each
        float rz = 1.f / z;
        uint4 w;
        u32 wq[4];
        #pragma unroll
        for (int q = 0; q < 4; q++){
            float f0 = eluf(acc[4 * q + 0] * rz + b1[16 * l + 4 * q + 0]);
            float f1 = eluf(acc[4 * q + 1] * rz + b1[16 * l + 4 * q + 1]);
            float f2 = eluf(acc[4 * q + 2] * rz + b1[16 * l + 4 * q + 2]);
            float f3 = eluf(acc[4 * q + 3] * rz + b1[16 * l + 4 * q + 3]);
            u32 lo = (u32)__builtin_amdgcn_cvt_pk_fp8_f32(f0, f1, 0, false);
            u32 hi = (u32)__builtin_amdgcn_cvt_pk_fp8_f32(f2, f3, 0, false);
            wq[q] = (lo & 0xFFFFu) | (hi << 16);
        }
        w.x = wq[0]; w.y = wq[1]; w.z = wq[2]; w.w = wq[3];
        ((uint4*)h1b)[(size_t)n * 8 + l] = w;
    }
}

// ================= GEMM 2 (fp8 in, fp8 h2b out + fused al_s2/al_d2 epilogue) =================
__global__ __launch_bounds__(256) void k_gemm2(const u8* __restrict__ hin, const float* __restrict__ W,
                                               const float* __restrict__ a2s, const float* __restrict__ a2d,
                                               u8* __restrict__ h2b,
                                               float* __restrict__ al_s, float* __restrict__ al_d){
    __shared__ __align__(16) u16 sW[32 * 136];
    int t = threadIdx.x;
    for (int i = t; i < 128 * 32; i += 256){
        int k = i >> 5, c = i & 31;
        sW[c * 136 + k] = f2bf(W[i]);
    }
    __syncthreads();
    int lane = t & 63, wave = t >> 6;
    int quad = lane >> 4, m16 = lane & 15;
    int rowA = blockIdx.x * 64 + wave * 16 + m16;
    bf16x8 afr[4];
    if (rowA < NN){
        const u8* xr = hin + (size_t)rowA * 128 + quad * 8;
        #pragma unroll
        for (int kk = 0; kk < 4; kk++){
            uint2 v = *(const uint2*)(xr + kk * 32);
            f32x2 d0 = __builtin_amdgcn_cvt_pk_f32_fp8(v.x, false);
            f32x2 d1 = __builtin_amdgcn_cvt_pk_f32_fp8(v.x, true);
            f32x2 d2 = __builtin_amdgcn_cvt_pk_f32_fp8(v.y, false);
            f32x2 d3 = __builtin_amdgcn_cvt_pk_f32_fp8(v.y, true);
            afr[kk][0] = (__bf16)d0[0]; afr[kk][1] = (__bf16)d0[1];
            afr[kk][2] = (__bf16)d1[0]; afr[kk][3] = (__bf16)d1[1];
            afr[kk][4] = (__bf16)d2[0]; afr[kk][5] = (__bf16)d2[1];
            afr[kk][6] = (__bf16)d3[0]; afr[kk][7] = (__bf16)d3[1];
        }
    } else {
        #pragma unroll
        for (int kk = 0; kk < 4; kk++)
            #pragma unroll
            for (int i2 = 0; i2 < 8; i2++) afr[kk][i2] = (__bf16)0.f;
    }
    int rowbase = blockIdx.x * 64 + wave * 16 + quad * 4;
    float vs2[4], vd2[4];
    #pragma unroll
    for (int r = 0; r < 4; r++){ vs2[r] = 0.f; vd2[r] = 0.f; }
    #pragma unroll
    for (int nt = 0; nt < 2; nt++){
        f32x4 acc = (f32x4){0.f, 0.f, 0.f, 0.f};
        const u16* wp = &sW[(nt * 16 + m16) * 136 + quad * 8];
        #pragma unroll
        for (int kk = 0; kk < 4; kk++){
            bf16x8 bfr = *(const bf16x8*)(wp + kk * 32);
            acc = __builtin_amdgcn_mfma_f32_16x16x32_bf16(afr[kk], bfr, acc, 0, 0, 0);
        }
        int col = nt * 16 + m16;
        float cs = a2s[col], cd = a2d[col];
        #pragma unroll
        for (int r = 0; r < 4; r++){
            vs2[r] += acc[r] * cs;
            vd2[r] += acc[r] * cd;
            float hi = __shfl_xor(acc[r], 1);
            u32 pk = (u32)__builtin_amdgcn_cvt_pk_fp8_f32(acc[r], hi, 0, false);
            u32 pk2 = (u32)__shfl_xor((int)pk, 2);
            if ((m16 & 3) == 0){
                int row = rowbase + r;
                if (row < NN){
                    u32 word = (pk & 0xFFFFu) | (pk2 << 16);
                    *(u32*)(h2b + (size_t)row * 32 + nt * 16 + m16) = word;
                }
            }
        }
    }
    #pragma unroll
    for (int r = 0; r < 4; r++)
        #pragma unroll
        for (int m = 1; m < 16; m <<= 1){
            vs2[r] += __shfl_xor(vs2[r], m);
            vd2[r] += __shfl_xor(vd2[r], m);
        }
    if (m16 < 4){
        int row = rowbase + m16;
        if (row < NN){
            al_s[row] = sel4f(vs2[0], vs2[1], vs2[2], vs2[3], m16);
            al_d[row] = sel4f(vd2[0], vd2[1], vd2[2], vd2[3], m16);
        }
    }
}

// ================= layer 2: FUSED softmax + aggregate (fp8 h2b gather, 3-deep pipeline) =================
__global__ __launch_bounds__(256) void k_node2(const int* __restrict__ src32, const u16* __restrict__ ale2p,
                                               const int* __restrict__ offsets,
                                               const float* __restrict__ al_s, const float* __restrict__ al_d,
                                               const u8* __restrict__ h2b, const float* __restrict__ b2,
                                               float* __restrict__ dout, float* __restrict__ rzv){
    int wave = threadIdx.x >> 6, lane = threadIdx.x & 63;
    int n = blockIdx.x * 4 + wave;
    int start = offsets[n], end = offsets[n + 1];
    int degr = end - start - 1;
    float aldn = al_d[n];
    int g = lane >> 3, l = lane & 7;                 // 8 edges in flight, channels l*4..l*4+3
    const u32* h2v = (const u32*)h2b;                // 8 u32 (4 fp8) per row
    f32x4 acc = (f32x4){0.f, 0.f, 0.f, 0.f};
    float z = 0.f, sa = 0.f;
    int i = start + 1 + g;
    int i1 = i + 8, i2 = i + 16;
    int src0 = (i  < end) ? __builtin_nontemporal_load(src32 + i)  : n;
    int src1 = (i1 < end) ? __builtin_nontemporal_load(src32 + i1) : n;
    float a0   = (i < end) ? bf2f(__builtin_nontemporal_load(ale2p + i)) : 0.f;
    float als0 = al_s[src0];
    u32 v0 = h2v[(size_t)src0 * 8 + l];
    while (i < end){
        int src2 = (i2 < end) ? __builtin_nontemporal_load(src32 + i2) : n;
        float a1v  = (i1 < end) ? bf2f(__builtin_nontemporal_load(ale2p + i1)) : 0.f;
        float als1 = al_s[src1];
        u32 v1 = h2v[(size_t)src1 * 8 + l];
        float e = __expf(lreluf(als0 + aldn + a0));
        z += e; sa += a0;
        f32x2 d0 = __builtin_amdgcn_cvt_pk_f32_fp8(v0, false);
        f32x2 d1 = __builtin_amdgcn_cvt_pk_f32_fp8(v0, true);
        acc[0] += e * d0[0]; acc[1] += e * d0[1];
        acc[2] += e * d1[0]; acc[3] += e * d1[1];
        i = i1; i1 = i2; i2 += 8;
        src1 = src2; a0 = a1v; als0 = als1; v0 = v1;
    }
    z += __shfl_xor(z, 8); z += __shfl_xor(z, 16); z += __shfl_xor(z, 32);
    sa += __shfl_xor(sa, 8); sa += __shfl_xor(sa, 16); sa += __shfl_xor(sa, 32);
    float mal = sa / fmaxf((float)degr, 1.f);
    float ps = __expf(lreluf(al_s[n] + aldn + mal));
    z += ps;
    float rz = 1.f / z;
    if (g == 0){                                     // self contribution
        u32 v = h2v[(size_t)n * 8 + l];
        f32x2 d0 = __builtin_amdgcn_cvt_pk_f32_fp8(v, false);
        f32x2 d1 = __builtin_amdgcn_cvt_pk_f32_fp8(v, true);
        acc[0] += ps * d0[0]; acc[1] += ps * d0[1];
        acc[2] += ps * d1[0]; acc[3] += ps * d1[1];
    }
    if (lane == 0){
        rzv[n] = rz;
        dout[OUT_AL + NE + n] = ps * rz;             // self-loop alpha
        dout[OUT_EI + NE + n] = (float)n;            // self-loop edge_index entries
        dout[OUT_EI + NE2 + NE + n] = (float)n;
    }
    #pragma unroll
    for (int k = 0; k < 4; k++){
        acc[k] += __shfl_xor(acc[k], 8);
        acc[k] += __shfl_xor(acc[k], 16);
        acc[k] += __shfl_xor(acc[k], 32);
    }
    if (g == 0){
        f32x4 w;
        #pragma unroll
        for (int k = 0; k < 4; k++) w[k] = eluf(acc[k] * rz + b2[l * 4 + k]);
        ((f32x4*)dout)[(size_t)n * 8 + l] = w;
    }
}

// alpha + edge_index for real edges, original edge order: all writes sequential
__global__ __launch_bounds__(256) void k_alpha(const int* __restrict__ ei, const u16* __restrict__ ale2,
                                               const float* __restrict__ al_s, const float* __restrict__ al_d,
                                               const float* __restrict__ rzv, float* __restrict__ dout){
    int e = blockIdx.x * 256 + threadIdx.x;          // NE exact
    int src = ei[e], dst = ei[NE + e];
    float a = bf2f(ale2[e]);
    float ev = __expf(lreluf(al_s[src] + al_d[dst] + a));
    __builtin_nontemporal_store(ev * rzv[dst], &dout[OUT_AL + e]);
    __builtin_nontemporal_store((float)src, &dout[OUT_EI + e]);
    __builtin_nontemporal_store((float)dst, &dout[OUT_EI + NE2 + e]);
}

extern "C" void kernel_launch(void* const* d_in, const int* in_sizes, int n_in,
                              void* d_out, int out_size, void* d_ws, size_t ws_size,
                              hipStream_t stream) {
    const float* x     = (const float*)d_in[0];
    const int*   ei    = (const int*)d_in[1];
    const float* eattr = (const float*)d_in[2];
    const float* W1    = (const float*)d_in[3];
    const float* W1e   = (const float*)d_in[4];
    const float* a1s   = (const float*)d_in[5];
    const float* a1d   = (const float*)d_in[6];
    const float* a1e   = (const float*)d_in[7];
    const float* b1    = (const float*)d_in[8];
    const float* W2    = (const float*)d_in[9];
    const float* W2e   = (const float*)d_in[10];
    const float* a2s   = (const float*)d_in[11];
    const float* a2d   = (const float*)d_in[12];
    const float* a2e   = (const float*)d_in[13];
    const float* b2    = (const float*)d_in[14];
    float* dout = (float*)d_out;

    char* ws = (char*)d_ws;
    size_t off = 0;
    auto alloc = [&](size_t bytes) -> void* {
        void* p = ws + off;
        off += (bytes + 255) & ~(size_t)255;
        return p;
    };
    // --- zero-initialized: bucket counters only ---
    int* bcnt = (int*)alloc((size_t)NB * 4);
    size_t zero_bytes = off;
    // --- rest fully written before read ---
    int*     offsets = (int*)alloc((size_t)(NN + 1) * 4);
    u32*     binsP   = (u32*)alloc((size_t)NB * CAP * 4);    // dead after k_fscatter
    uint2*   binsA   = (uint2*)alloc((size_t)NB * CAP * 8);  // dead after k_fscatter
    u16*     binsA2  = (u16*)alloc((size_t)NB * CAP * 2);    // dead after k_fscatter
    int*     src32   = (int*)alloc((size_t)NE2 * 4);
    uint2*   ale1p   = (uint2*)alloc((size_t)NE2 * 8);
    u16*     ale2p   = (u16*)alloc((size_t)NE2 * 2);
    u16*     ale2seq = (u16*)alloc((size_t)NE * 2);          // live until k_alpha
    float*   al_s1   = (float*)alloc((size_t)NN * 4 * 4);
    float*   al_d1   = (float*)alloc((size_t)NN * 4 * 4);
    u8*      h1      = (u8*)alloc((size_t)NN * 128);         // fp8; dead after k_node1
    // aliases into dead regions:
    u8*    h1b   = (u8*)binsP;                               // fp8 12.8 MB in binsP+binsA (24 MB, dead after fscatter)
    char*  h1r   = (char*)h1;                                // h1 region (12.8 MB) reused after k_node1:
    u8*    h2b   = (u8*)h1r;                                 //   NN*32 = 3.2 MB (fp8)
    float* al_s2 = (float*)(h1r + 3200000);                  //   NN*4
    float* al_d2 = al_s2 + NNP;
    float* rzv   = al_d2 + NNP;

    const int TB = 256;
    hipMemsetAsync(d_ws, 0, zero_bytes, stream);

    // bucketed CSR build (edge logits fused into bscatter)
    k_bscatter<<<NBB, TB, 0, stream>>>(ei, eattr, W1e, a1e, W2e, a2e, bcnt, binsP, binsA, binsA2, ale2seq);
    k_fscatter<<<NB, TB, 0, stream>>>(binsP, binsA, binsA2, bcnt, offsets, src32, ale1p, ale2p);
    // layer 1
    k_gemm1<<<(NN + 63) / 64, TB, 0, stream>>>(x, W1, a1s, a1d, h1, al_s1, al_d1);
    k_node1<<<NN / 4, TB, 0, stream>>>(src32, (const u16*)ale1p, offsets, al_s1, al_d1, h1, b1, h1b);
    // layer 2 (h1 region reused as h2b/al2/rzv)
    k_gemm2<<<(NN + 63) / 64, TB, 0, stream>>>(h1b, W2, a2s, a2d, h2b, al_s2, al_d2);
    k_node2<<<NN / 4, TB, 0, stream>>>(src32, ale2p, offsets, al_s2, al_d2, h2b, b2, dout, rzv);
    k_alpha<<<NE / TB, TB, 0, stream>>>(ei, ale2seq, al_s2, al_d2, rzv, dout);
}